// Round 16
// baseline (3676.088 us; speedup 1.0000x reference)
//
#include <hip/hip_runtime.h>
#include <hip/hip_bf16.h>
#include <math.h>

#define DD 384
#define NBATCH 64
#define NSEQ 721
#define NROWS (NBATCH*NSEQ)   // 46144
#define NLAYER 4
#define VTW 736               // padded token width for transposed V (mult of 8)

typedef __bf16 bf16_t;
typedef __bf16 bf16x8 __attribute__((ext_vector_type(8)));
typedef float  f32x4  __attribute__((ext_vector_type(4)));

static __device__ __forceinline__ void split_bf16(float v, bf16_t& h, bf16_t& l) {
    h = (bf16_t)v;
    l = (bf16_t)(v - (float)h);
}
static __device__ __forceinline__ bf16x8 bzero8() {
    bf16x8 v = {(bf16_t)0.f,(bf16_t)0.f,(bf16_t)0.f,(bf16_t)0.f,
                (bf16_t)0.f,(bf16_t)0.f,(bf16_t)0.f,(bf16_t)0.f};
    return v;
}
// async global->LDS, 16B per lane; LDS dest is wave-uniform base + lane*16,
// global source is PER-LANE.
static __device__ __forceinline__ void gload16(const void* g, void* l) {
    __builtin_amdgcn_global_load_lds(
        (const __attribute__((address_space(1))) unsigned int*)g,
        (__attribute__((address_space(3))) unsigned int*)l, 16, 0, 0);
}
// m204 bijective XCD swizzle
static __device__ __forceinline__ int xcd_swz(int nwg) {
    int orig = blockIdx.x;
    int q = nwg >> 3, r = nwg & 7;
    int xcd = orig & 7, within = orig >> 3;
    int base = (xcd < r) ? xcd*(q+1) : r*(q+1) + (xcd - r)*q;
    return base + within;
}
// reconstruct LN terms from 6 partial sums (slots stride NROWS)
static __device__ __forceinline__ void ln_from_partials(const float* ss, const float* ss2,
                                                        int row, float& mu, float& rstd) {
    float s = 0.f, q2 = 0.f;
    #pragma unroll
    for (int k = 0; k < 6; ++k) { s += ss[k*NROWS + row]; q2 += ss2[k*NROWS + row]; }
    mu = s * (1.f/DD);
    float var = q2 * (1.f/DD) - mu*mu;
    rstd = rsqrtf(var + 1e-5f);
}

// ---------------------------------------------------------------- build x (split residual + ln1 stats)
__global__ __launch_bounds__(256) void build_x_kernel(const float* __restrict__ search,
                               const float* __restrict__ target,
                               const float* __restrict__ cls,
                               const float* __restrict__ spos,
                               const float* __restrict__ tpos,
                               bf16_t* __restrict__ xh, bf16_t* __restrict__ xl,
                               float* __restrict__ wss, float* __restrict__ wss2) {
    int wave = threadIdx.x >> 6, lane = threadIdx.x & 63;
    int row = blockIdx.x * 4 + wave;
    if (row >= NROWS) return;
    int b = row / NSEQ, n = row % NSEQ;
    float s = 0.f, q2 = 0.f;
    #pragma unroll
    for (int i = 0; i < 6; ++i) {
        int d = lane + 64*i;
        float val;
        if (n == 0)        val = cls[d];
        else if (n <= 576) val = search[((size_t)b*576 + (n-1))*DD + d] + spos[(size_t)(n-1)*DD + d];
        else               val = target[((size_t)b*144 + (n-577))*DD + d] + tpos[(size_t)(n-577)*DD + d];
        bf16_t h, l;
        split_bf16(val, h, l);
        xh[(size_t)row*DD + d] = h;
        xl[(size_t)row*DD + d] = l;
        s += val; q2 += val*val;
    }
    #pragma unroll
    for (int m = 1; m < 64; m <<= 1) { s += __shfl_xor(s, m); q2 += __shfl_xor(q2, m); }
    if (lane == 0) {
        wss[row] = s; wss2[row] = q2;
        #pragma unroll
        for (int k = 1; k < 6; ++k) { wss[k*NROWS + row] = 0.f; wss2[k*NROWS + row] = 0.f; }
    }
}

// ---------------------------------------------------------------- weight prep
__global__ void transpose_split_kernel(const float* __restrict__ src,
                                       const float* __restrict__ g,
                                       bf16_t* __restrict__ dh,
                                       bf16_t* __restrict__ dl,
                                       int K, int N) {
    int idx = blockIdx.x * blockDim.x + threadIdx.x;
    if (idx >= K*N) return;
    int k = idx / N, n = idx % N;
    float v = src[idx];
    if (g) v *= g[k];
    bf16_t h, l;
    split_bf16(v, h, l);
    dh[(size_t)n*K + k] = h;
    dl[(size_t)n*K + k] = l;
}

// colsums for LN-fold
__global__ void colsum_kernel(const float* __restrict__ W, const float* __restrict__ g,
                              const float* __restrict__ b, const float* __restrict__ bias,
                              float* __restrict__ c1, float* __restrict__ c2,
                              int K, int N, int outStride, int outOff) {
    int l = blockIdx.y;
    int n = blockIdx.x * 256 + threadIdx.x;
    if (n >= N) return;
    const float* Wl = W + (size_t)l*K*N;
    const float* gl = g + (size_t)l*K;
    const float* bl = b + (size_t)l*K;
    float s1 = 0.f, s2 = 0.f;
    for (int k = 0; k < K; ++k) {
        float w = Wl[(size_t)k*N + n];
        s1 = fmaf(gl[k], w, s1);
        s2 = fmaf(bl[k], w, s2);
    }
    c1[(size_t)l*outStride + outOff + n] = s1;
    c2[(size_t)l*outStride + outOff + n] = s2 + bias[(size_t)l*N + n];
}

// ---------------------------------------------------------------- GEMM cores
// core3: 3-pass split (AhBh + AhBl + AlBh), 32 slots / 32KB staging.
static __device__ __forceinline__ void gemm_core3(
        const bf16_t* __restrict__ ah, const bf16_t* __restrict__ al,
        const bf16_t* __restrict__ bh, const bf16_t* __restrict__ bl,
        bf16_t (&ls)[32][64][8],
        int m0, int n0, int K, f32x4 (&acc)[4][4]) {
    int t = threadIdx.x;
    int w = t >> 6, lane = t & 63;
    int c = lane & 15, g = lane >> 4;
    int wr = w >> 1, wc = w & 1;
    const bf16_t* src0 = (w==0) ? ah : (w==1) ? al : (w==2) ? bh : bl;
    int base_rc = (w < 2) ? m0 : n0;
    const bf16_t* srcbase = src0 + (size_t)(base_rc + c)*K + 8*g;

    int ksteps = K >> 5;
    for (int kt = 0; kt < ksteps; ++kt) {
        int k0 = kt << 5;
        __syncthreads();
        #pragma unroll
        for (int i = 0; i < 8; ++i)
            gload16(srcbase + (size_t)(16*i)*K + k0, &ls[w*8 + i][0][0]);
        __syncthreads();
        bf16x8 af_h[4], af_l[4], bf_h[4], bf_l[4];
        #pragma unroll
        for (int i = 0; i < 4; ++i) {
            af_h[i] = *(const bf16x8*)&ls[     4*wr + i][lane][0];
            af_l[i] = *(const bf16x8*)&ls[ 8 + 4*wr + i][lane][0];
            bf_h[i] = *(const bf16x8*)&ls[16 + 4*wc + i][lane][0];
            bf_l[i] = *(const bf16x8*)&ls[24 + 4*wc + i][lane][0];
        }
        #pragma unroll
        for (int i = 0; i < 4; ++i)
            #pragma unroll
            for (int j = 0; j < 4; ++j) {
                acc[i][j] = __builtin_amdgcn_mfma_f32_16x16x32_bf16(af_h[i], bf_h[j], acc[i][j], 0,0,0);
                acc[i][j] = __builtin_amdgcn_mfma_f32_16x16x32_bf16(af_h[i], bf_l[j], acc[i][j], 0,0,0);
                acc[i][j] = __builtin_amdgcn_mfma_f32_16x16x32_bf16(af_l[i], bf_h[j], acc[i][j], 0,0,0);
            }
    }
}

// core2: 2-pass (A single bf16; B hi/lo exact) = A@(Bh+Bl). 24 slots staged
// (slots 0-7 A, 8-15 Bh, 16-23 Bl), 6 loads/wave/step, 32 MFMA/step.
static __device__ __forceinline__ void gemm_core2(
        const bf16_t* __restrict__ ah,
        const bf16_t* __restrict__ bh, const bf16_t* __restrict__ bl,
        bf16_t (&ls)[32][64][8],
        int m0, int n0, int K, f32x4 (&acc)[4][4]) {
    int t = threadIdx.x;
    int w = t >> 6, lane = t & 63;
    int c = lane & 15, g = lane >> 4;
    int wr = w >> 1, wc = w & 1;

    int ksteps = K >> 5;
    for (int kt = 0; kt < ksteps; ++kt) {
        int k0 = kt << 5;
        __syncthreads();
        #pragma unroll
        for (int i = 0; i < 6; ++i) {
            int s = w*6 + i;                         // wave-uniform slot id
            const bf16_t* src = (s < 8) ? ah : (s < 16) ? bh : bl;
            int base = (s < 8) ? m0 : n0;
            int row = base + (s & 7)*16 + c;
            gload16(src + (size_t)row*K + k0 + 8*g, &ls[s][0][0]);
        }
        __syncthreads();
        bf16x8 af[4], bfh[4], bfl[4];
        #pragma unroll
        for (int i = 0; i < 4; ++i) {
            af[i]  = *(const bf16x8*)&ls[     4*wr + i][lane][0];
            bfh[i] = *(const bf16x8*)&ls[ 8 + 4*wc + i][lane][0];
            bfl[i] = *(const bf16x8*)&ls[16 + 4*wc + i][lane][0];
        }
        #pragma unroll
        for (int i = 0; i < 4; ++i)
            #pragma unroll
            for (int j = 0; j < 4; ++j) {
                acc[i][j] = __builtin_amdgcn_mfma_f32_16x16x32_bf16(af[i], bfh[j], acc[i][j], 0,0,0);
                acc[i][j] = __builtin_amdgcn_mfma_f32_16x16x32_bf16(af[i], bfl[j], acc[i][j], 0,0,0);
            }
    }
}

// ---------------------------------------------------------------- fused QKV GEMM (LN-folded, 2-pass)
// Batch-aligned m-tiles (6/batch). Outputs coalesced via in-LDS regroup.
// V pad tokens forced to ZERO (NaN-garbage would poison PV; round-11 lesson).
__global__ __launch_bounds__(256, 4) void gemm_qkv(
        const bf16_t* __restrict__ ah,
        const bf16_t* __restrict__ bh, const bf16_t* __restrict__ bl,
        const float* __restrict__ ss, const float* __restrict__ ss2,
        const float* __restrict__ c1, const float* __restrict__ c2,
        bf16_t* __restrict__ qout, bf16_t* __restrict__ kout,
        bf16_t* __restrict__ vth,
        int nwg) {
    __shared__ __align__(16) bf16_t ls[32][64][8];
    int wgid = xcd_swz(nwg);
    int mt = wgid / 9, n0 = (wgid % 9) * 128;
    int blb = mt / 6;
    int tok_base = (mt % 6) * 128;
    int m0d = blb*NSEQ + tok_base;           // contiguous data rows (tail reads spill, discarded)
    f32x4 zero4 = {0.f,0.f,0.f,0.f};
    f32x4 acc[4][4];
    #pragma unroll
    for (int i = 0; i < 4; ++i)
        #pragma unroll
        for (int j = 0; j < 4; ++j) acc[i][j] = zero4;
    gemm_core2(ah, bh, bl, ls, m0d, n0, DD, acc);

    int t = threadIdx.x, w = t >> 6, lane = t & 63;
    int c = lane & 15, g = lane >> 4;
    int wr = w >> 1, wc = w & 1;
    // hoisted per-row LN terms (valid tokens only)
    float rmu[16], rrs[16];
    #pragma unroll
    for (int i = 0; i < 4; ++i)
        #pragma unroll
        for (int r = 0; r < 4; ++r) {
            int tok = tok_base + 64*wr + 16*i + 4*g + r;
            float mu = 0.f, rstd = 1.f;
            if (tok < NSEQ) ln_from_partials(ss, ss2, blb*NSEQ + tok, mu, rstd);
            rmu[i*4+r] = mu; rrs[i*4+r] = rstd;
        }
    int seg = n0 / 384;                      // 0=Q 1=K 2=V
    bf16_t* LST = &ls[0][0][0];              // 128x128 bf16 regroup buffer (32KB)
    if (seg < 2) {
        bf16_t* outb = (seg == 0) ? qout : kout;
        int segoff = seg * 384;
        __syncthreads();                     // core done reading ls
        #pragma unroll
        for (int j = 0; j < 4; ++j) {
            int nl = 64*wc + 16*j + c;       // tile-local n 0..127
            float C1 = c1[n0 + nl], C2 = c2[n0 + nl];
            #pragma unroll
            for (int i = 0; i < 4; ++i)
                #pragma unroll
                for (int r = 0; r < 4; ++r) {
                    int rl = 64*wr + 16*i + 4*g + r;   // tile-local row 0..127
                    float val = rrs[i*4+r]*(acc[i][j][r] - rmu[i*4+r]*C1) + C2;
                    LST[rl*128 + (nl ^ ((rl & 15) << 3))] = (bf16_t)val;
                }
        }
        __syncthreads();
        #pragma unroll
        for (int p = 0; p < 8; ++p) {
            int chunk = t + 256*p;
            int rl = chunk >> 4;
            int nl0 = (chunk & 15) * 8;
            int tok = tok_base + rl;
            if (tok >= NSEQ) continue;
            uint4 v = *(const uint4*)&LST[rl*128 + (nl0 ^ ((rl & 15) << 3))];
            *(uint4*)(outb + (size_t)(blb*NSEQ + tok)*DD + (n0 - segoff) + nl0) = v;
        }
    } else {
        int vbase = n0 - 768;                // 0 / 128 / 256
        __syncthreads();                     // core done reading ls
        #pragma unroll
        for (int j = 0; j < 4; ++j) {
            int d = 64*wc + 16*j + c;
            float C1 = c1[n0 + d], C2 = c2[n0 + d];
            #pragma unroll
            for (int i = 0; i < 4; ++i)
                #pragma unroll
                for (int r = 0; r < 4; ++r) {
                    int tokl = 64*wr + 16*i + 4*g + r;   // local 0..127
                    float val = rrs[i*4+r]*(acc[i][j][r] - rmu[i*4+r]*C1) + C2;
                    if (tok_base + tokl >= NSEQ) val = 0.f;   // kill NaN garbage in pad
                    LST[d*128 + (tokl ^ ((d & 15) << 3))] = (bf16_t)val;
                }
        }
        __syncthreads();
        #pragma unroll
        for (int p = 0; p < 8; ++p) {
            int chunk = t + 256*p;
            int d = chunk >> 4;
            int tok0 = (chunk & 15) * 8;
            int tg = tok_base + tok0;
            if (tg + 8 > VTW) continue;      // don't spill into next d-row
            uint4 v = *(const uint4*)&LST[d*128 + (tok0 ^ ((d & 15) << 3))];
            *(uint4*)(vth + ((size_t)(blb*DD + vbase + d))*VTW + tg) = v;
        }
    }
}

// ---------------------------------------------------------------- M1: LN-folded gelu GEMM (2-pass A)
// out hi/lo [M][768], coalesced via regroup (val parked in acc between passes)
__global__ __launch_bounds__(256, 4) void gemm_m1(
        const bf16_t* __restrict__ ah,
        const bf16_t* __restrict__ bh, const bf16_t* __restrict__ bl,
        const float* __restrict__ ss, const float* __restrict__ ss2,
        const float* __restrict__ c1, const float* __restrict__ c2,
        bf16_t* __restrict__ o1, bf16_t* __restrict__ o2,
        int M, int nwg) {
    __shared__ __align__(16) bf16_t ls[32][64][8];
    int wgid = xcd_swz(nwg);
    int m0 = (wgid / 6) * 128, n0 = (wgid % 6) * 128;
    f32x4 zero4 = {0.f,0.f,0.f,0.f};
    f32x4 acc[4][4];
    #pragma unroll
    for (int i = 0; i < 4; ++i)
        #pragma unroll
        for (int j = 0; j < 4; ++j) acc[i][j] = zero4;
    gemm_core2(ah, bh, bl, ls, m0, n0, DD, acc);

    int t = threadIdx.x, w = t >> 6, lane = t & 63;
    int c = lane & 15, g = lane >> 4;
    int wr = w >> 1, wc = w & 1;
    float rmu[16], rrs[16];
    #pragma unroll
    for (int i = 0; i < 4; ++i)
        #pragma unroll
        for (int r = 0; r < 4; ++r) {
            int row = m0 + 64*wr + 16*i + 4*g + r;
            float mu = 0.f, rstd = 1.f;
            if (row < M) ln_from_partials(ss, ss2, row, mu, rstd);
            rmu[i*4+r] = mu; rrs[i*4+r] = rstd;
        }
    bf16_t* LST = &ls[0][0][0];
    __syncthreads();                         // core done reading ls
    // pass 0: compute val (LN fold + gelu), park in acc, write hi
    #pragma unroll
    for (int j = 0; j < 4; ++j) {
        int nl = 64*wc + 16*j + c;
        float C1 = c1[n0 + nl], C2 = c2[n0 + nl];
        #pragma unroll
        for (int i = 0; i < 4; ++i)
            #pragma unroll
            for (int r = 0; r < 4; ++r) {
                int rl = 64*wr + 16*i + 4*g + r;
                float val = rrs[i*4+r]*(acc[i][j][r] - rmu[i*4+r]*C1) + C2;
                val = 0.5f*val*(1.0f + erff(val*0.70710678118654752f));
                acc[i][j][r] = val;
                LST[rl*128 + (nl ^ ((rl & 15) << 3))] = (bf16_t)val;
            }
    }
    __syncthreads();
    #pragma unroll
    for (int p = 0; p < 8; ++p) {
        int chunk = t + 256*p;
        int rl = chunk >> 4;
        int nl0 = (chunk & 15) * 8;
        int row = m0 + rl;
        if (row >= M) continue;
        uint4 v = *(const uint4*)&LST[rl*128 + (nl0 ^ ((rl & 15) << 3))];
        *(uint4*)(o1 + (size_t)row*768 + n0 + nl0) = v;
    }
    __syncthreads();
    // pass 1: lo = val - hi
    #pragma unroll
    for (int j = 0; j < 4; ++j) {
        int nl = 64*wc + 16*j + c;
        #pragma unroll
        for (int i = 0; i < 4; ++i)
            #pragma unroll
            for (int r = 0; r < 4; ++r) {
                int rl = 64*wr + 16*i + 4*g + r;
                float val = acc[i][j][r];
                bf16_t h, l;
                split_bf16(val, h, l);
                LST[rl*128 + (nl ^ ((rl & 15) << 3))] = l;
            }
    }
    __syncthreads();
    #pragma unroll
    for (int p = 0; p < 8; ++p) {
        int chunk = t + 256*p;
        int rl = chunk >> 4;
        int nl0 = (chunk & 15) * 8;
        int row = m0 + rl;
        if (row >= M) continue;
        uint4 v = *(const uint4*)&LST[rl*128 + (nl0 ^ ((rl & 15) << 3))];
        *(uint4*)(o2 + (size_t)row*768 + n0 + nl0) = v;
    }
}

// ---------------------------------------------------------------- M2: residual-update GEMM (3-pass)
// x += mid@W2 + b2; writes split residual hi/lo coalesced + ln2-stat partials
__global__ __launch_bounds__(256, 4) void gemm_m2(
        const bf16_t* __restrict__ ah, const bf16_t* __restrict__ al,
        const bf16_t* __restrict__ bh, const bf16_t* __restrict__ bl,
        const float* __restrict__ bias,
        const bf16_t* __restrict__ resh, const bf16_t* __restrict__ resl,
        bf16_t* __restrict__ o1, bf16_t* __restrict__ o2,
        float* __restrict__ wss, float* __restrict__ wss2,
        int M, int nwg) {
    __shared__ __align__(16) bf16_t ls[32][64][8];
    int wgid = xcd_swz(nwg);
    int m0 = (wgid / 3) * 128, n0 = (wgid % 3) * 128;
    f32x4 zero4 = {0.f,0.f,0.f,0.f};
    f32x4 acc[4][4];
    #pragma unroll
    for (int i = 0; i < 4; ++i)
        #pragma unroll
        for (int j = 0; j < 4; ++j) acc[i][j] = zero4;
    gemm_core3(ah, al, bh, bl, ls, m0, n0, 768, acc);

    int t = threadIdx.x, w = t >> 6, lane = t & 63;
    int c = lane & 15, g = lane >> 4;
    int wr = w >> 1, wc = w & 1;
    int slot = (wgid % 3) + 3*wc;            // stat slots 0..5
    bf16_t* LST = &ls[0][0][0];
    __syncthreads();                         // core done reading ls
    // pass 0: compute val (+bias +residual), stats, park in acc, write hi
    #pragma unroll
    for (int i = 0; i < 4; ++i)
        #pragma unroll
        for (int r = 0; r < 4; ++r) {
            int rl = 64*wr + 16*i + 4*g + r;
            int row = m0 + rl;
            float s = 0.f, q2 = 0.f;
            if (row < M) {
                #pragma unroll
                for (int j = 0; j < 4; ++j) {
                    int nl = 64*wc + 16*j + c;
                    size_t o = (size_t)row*DD + n0 + nl;
                    float val = acc[i][j][r] + bias[n0 + nl] + (float)resh[o] + (float)resl[o];
                    acc[i][j][r] = val;
                    LST[rl*128 + (nl ^ ((rl & 15) << 3))] = (bf16_t)val;
                    s += val; q2 += val*val;
                }
            }
            #pragma unroll
            for (int m = 1; m < 16; m <<= 1) { s += __shfl_xor(s, m); q2 += __shfl_xor(q2, m); }
            if (row < M && c == 0) {
                wss[slot*NROWS + row] = s;
                wss2[slot*NROWS + row] = q2;
            }
        }
    __syncthreads();
    #pragma unroll
    for (int p = 0; p < 8; ++p) {
        int chunk = t + 256*p;
        int rl = chunk >> 4;
        int nl0 = (chunk & 15) * 8;
        int row = m0 + rl;
        if (row >= M) continue;
        uint4 v = *(const uint4*)&LST[rl*128 + (nl0 ^ ((rl & 15) << 3))];
        *(uint4*)(o1 + (size_t)row*DD + n0 + nl0) = v;
    }
    __syncthreads();
    // pass 1: lo
    #pragma unroll
    for (int i = 0; i < 4; ++i)
        #pragma unroll
        for (int r = 0; r < 4; ++r) {
            int rl = 64*wr + 16*i + 4*g + r;
            if (m0 + rl >= M) continue;
            #pragma unroll
            for (int j = 0; j < 4; ++j) {
                int nl = 64*wc + 16*j + c;
                bf16_t h, l;
                split_bf16(acc[i][j][r], h, l);
                LST[rl*128 + (nl ^ ((rl & 15) << 3))] = l;
            }
        }
    __syncthreads();
    #pragma unroll
    for (int p = 0; p < 8; ++p) {
        int chunk = t + 256*p;
        int rl = chunk >> 4;
        int nl0 = (chunk & 15) * 8;
        int row = m0 + rl;
        if (row >= M) continue;
        uint4 v = *(const uint4*)&LST[rl*128 + (nl0 ^ ((rl & 15) << 3))];
        *(uint4*)(o2 + (size_t)row*DD + n0 + nl0) = v;
    }
}

// ---------------------------------------------------------------- MFMA attention
// 4 waves / 64 q-rows; K + V-hi DMA-staged (48KB LDS). __launch_bounds__(256,2)
// pins 2 blk/CU (proven L2-friendly residency; rounds 12-15 A/B).
// PV 2-pass Vh*(Ph+Pl); defer-max (T13).
__global__ __launch_bounds__(256, 2) void attn_mfma(
        const bf16_t* __restrict__ qh, const bf16_t* __restrict__ kh,
        const bf16_t* __restrict__ vth,
        bf16_t* __restrict__ xh, bf16_t* __restrict__ xl,
        float* __restrict__ wss, float* __restrict__ wss2, int nwg) {
    __shared__ __align__(16) char smem[49152];
    bf16_t* kf = (bf16_t*)smem;              // 24 slots x 1KB  (K tile)
    char* vhp = smem + 24576;                // 24KB V-hi

    int t = threadIdx.x, w = t >> 6, lane = t & 63;
    int c = lane & 15, g = lane >> 4;
    int wgid = xcd_swz(nwg);
    int bl_ = wgid / 12;
    int q0 = (wgid % 12) * 64;
    size_t bb = (size_t)bl_ * NSEQ;
    int qrow = q0 + 16*w + c;
    bool qok = (qrow < NSEQ);
    const float scale = 0.05103103630798287f;   // 384^-0.5
    int vswz = (c ^ (c >> 2)) & 3;              // PV read slot swizzle
    int dma_dd  = lane >> 2;                    // V DMA lane mapping
    int dma_kv8 = (lane & 3) ^ ((dma_dd ^ (dma_dd >> 2)) & 3);

    bf16x8 qf[12];
    #pragma unroll
    for (int ks = 0; ks < 12; ++ks) {
        if (qok) qf[ks] = *(const bf16x8*)(qh + (bb + qrow)*DD + 32*ks + 8*g);
        else     qf[ks] = bzero8();
    }

    f32x4 zero4 = {0.f,0.f,0.f,0.f};
    f32x4 oacc[24];
    #pragma unroll
    for (int i = 0; i < 24; ++i) oacc[i] = zero4;
    float m_run = -1e30f, l_run = 0.f;

    // prologue: issue K(0)
    #pragma unroll
    for (int i = 0; i < 6; ++i) {
        int s = i*4 + w;
        int ks = s >> 1, mf = s & 1;
        gload16(kh + (bb + (size_t)(16*mf + c))*DD + 32*ks + 8*g, kf + s*512);
    }

    for (int kt = 0; kt < 23; ++kt) {
        int kv0 = kt * 32;
        asm volatile("s_waitcnt vmcnt(0)" ::: "memory");   // K(kt) landed
        __builtin_amdgcn_s_barrier();
        // issue V(kt): flight hides under QK+softmax
        #pragma unroll
        for (int i = 0; i < 6; ++i) {
            int s = i*4 + w;
            size_t gro = ((size_t)(bl_*DD + 16*s + dma_dd))*VTW + kv0 + 8*dma_kv8;
            gload16(vth + gro, (bf16_t*)vhp + s*512);
        }
        // ---- QK: S^T = K * Q^T
        f32x4 sacc[2];
        sacc[0] = zero4; sacc[1] = zero4;
        #pragma unroll
        for (int ks = 0; ks < 12; ++ks) {
            bf16x8 a0 = *(const bf16x8*)(kf + ((size_t)(2*ks+0)*64 + lane)*8);
            bf16x8 a1 = *(const bf16x8*)(kf + ((size_t)(2*ks+1)*64 + lane)*8);
            sacc[0] = __builtin_amdgcn_mfma_f32_16x16x32_bf16(a0, qf[ks], sacc[0], 0,0,0);
            sacc[1] = __builtin_amdgcn_mfma_f32_16x16x32_bf16(a1, qf[ks], sacc[1], 0,0,0);
        }
        // ---- online softmax with defer-max
        float p[2][4];
        float mx = -1e30f;
        #pragma unroll
        for (int mf = 0; mf < 2; ++mf)
            #pragma unroll
            for (int r = 0; r < 4; ++r) {
                float sv = sacc[mf][r] * scale;
                int kv = kv0 + 16*mf + 4*g + r;
                if (kv >= NSEQ) sv = -1e30f;
                p[mf][r] = sv;
                mx = fmaxf(mx, sv);
            }
        mx = fmaxf(mx, __shfl_xor(mx, 16));
        mx = fmaxf(mx, __shfl_xor(mx, 32));
        bool skip = __all(mx <= m_run + 8.f);   // P bounded by e^8: safe in f32
        float m_new = skip ? m_run : fmaxf(m_run, mx);
        float psum = 0.f;
        #pragma unroll
        for (int mf = 0; mf < 2; ++mf)
            #pragma unroll
            for (int r = 0; r < 4; ++r) {
                float pv = __expf(p[mf][r] - m_new);
                p[mf][r] = pv;
                psum += pv;
            }
        psum += __shfl_xor(psum, 16);
        psum += __shfl_xor(psum, 32);
        if (!skip) {
            float corr = __expf(m_run - m_new);
            l_run = l_run * corr + psum;
            #pragma unroll
            for (int i = 0; i < 24; ++i) oacc[i] *= corr;
            m_run = m_new;
        } else {
            l_run += psum;
        }
        bf16x8 ph, pl;
        #pragma unroll
        for (int mf = 0; mf < 2; ++mf)
            #pragma unroll
            for (int r = 0; r < 4; ++r) {
                bf16_t hh, ll;
                split_bf16(p[mf][r], hh, ll);
                ph[mf*4 + r] = hh;
                pl[mf*4 + r] = ll;
            }
        asm volatile("s_waitcnt vmcnt(0)" ::: "memory");   // V(kt) landed
        __builtin_amdgcn_s_barrier();
        // issue K(kt+1): flight hides under PV
        if (kt + 1 < 23) {
            int kv0n = kv0 + 32;
            #pragma unroll
            for (int i = 0; i < 6; ++i) {
                int s = i*4 + w;
                int ks = s >> 1, mf = s & 1;
                gload16(kh + (bb + (size_t)(kv0n + 16*mf + c))*DD + 32*ks + 8*g, kf + s*512);
            }
        }
        // ---- PV: O^T += Vh^T * (Ph + Pl)  (2-pass)
        #pragma unroll
        for (int mf = 0; mf < 24; ++mf) {
            int dr = 16*mf + c;
            const char* vb = vhp + dr*64;
            int o0 = ((((g>>1)     ^ vswz) << 4) | (8*(g&1)));
            int o1 = (((2 + (g>>1)) ^ vswz) << 4) | (8*(g&1));
            union { uint2 u[2]; bf16x8 v; } va;
            va.u[0] = *(const uint2*)(vb + o0);
            va.u[1] = *(const uint2*)(vb + o1);
            oacc[mf] = __builtin_amdgcn_mfma_f32_16x16x32_bf16(va.v, ph, oacc[mf], 0,0,0);
            oacc[mf] = __builtin_amdgcn_mfma_f32_16x16x32_bf16(va.v, pl, oacc[mf], 0,0,0);
        }
    }
    float inv = 1.f / l_run;
    float s = 0.f, q2 = 0.f;
    if (qok) {
        bf16_t* xhr = xh + (bb + qrow)*DD;
        bf16_t* xlr = xl + (bb + qrow)*DD;
        #pragma unroll
        for (int mf = 0; mf < 24; ++mf)
            #pragma unroll
            for (int r = 0; r < 4; ++r) {
                int d = 16*mf + 4*g + r;
                float xv = (float)xhr[d] + (float)xlr[d] + oacc[mf][r]*inv;
                bf16_t h, l;
                split_bf16(xv, h, l);
                xhr[d] = h;
                xlr[d] = l;
                s += xv; q2 += xv*xv;
            }
    }
    s += __shfl_xor(s, 16);  q2 += __shfl_xor(q2, 16);
    s += __shfl_xor(s, 32);  q2 += __shfl_xor(q2, 32);
    if (qok && g == 0) {
        int rowL = bl_*NSEQ + qrow;
        wss[rowL] = s; wss2[rowL] = q2;
        #pragma unroll
        for (int k = 1; k < 6; ++k) { wss[k*NROWS + rowL] = 0.f; wss2[k*NROWS + rowL] = 0.f; }
    }
}

// ---------------------------------------------------------------- head (f32)
__global__ __launch_bounds__(384) void head_kernel(const bf16_t* __restrict__ xh,
    const bf16_t* __restrict__ xl,
    const float* __restrict__ g, const float* __restrict__ bb,
    const float* __restrict__ Wl1, const float* __restrict__ bl1,
    const float* __restrict__ Wl2, const float* __restrict__ bl2,
    float* __restrict__ outp) {
    __shared__ float yv[384];
    __shared__ float r1[6], r2[6], r3[6];
    int b = blockIdx.x, t = threadIdx.x;
    size_t o = (size_t)b*NSEQ*DD + t;
    float v = (float)xh[o] + (float)xl[o];
    float s = v;
    #pragma unroll
    for (int m = 1; m < 64; m <<= 1) s += __shfl_xor(s, m);
    if ((t & 63) == 0) r1[t>>6] = s;
    __syncthreads();
    float mu = (r1[0]+r1[1]+r1[2]+r1[3]+r1[4]+r1[5]) * (1.f/384.f);
    float dd = v - mu;
    float sq = dd*dd;
    #pragma unroll
    for (int m = 1; m < 64; m <<= 1) sq += __shfl_xor(sq, m);
    if ((t & 63) == 0) r2[t>>6] = sq;
    __syncthreads();
    float var = (r2[0]+r2[1]+r2[2]+r2[3]+r2[4]+r2[5]) * (1.f/384.f);
    float rstd = rsqrtf(var + 1e-5f);
    yv[t] = dd*rstd*g[t] + bb[t];
    __syncthreads();
    float acc = bl1[t];
    for (int d2 = 0; d2 < 384; d2++) acc = fmaf(yv[d2], Wl1[d2*384 + t], acc);
    acc = fmaxf(acc, 0.f);
    float oo = acc * Wl2[t];
    #pragma unroll
    for (int m = 1; m < 64; m <<= 1) oo += __shfl_xor(oo, m);
    if ((t & 63) == 0) r3[t>>6] = oo;
    __syncthreads();
    if (t == 0) outp[b] = r3[0]+r3[1]+r3[2]+r3[3]+r3[4]+r3[5] + bl2[0];
}

// ---------------------------------------------------------------- launch
extern "C" void kernel_launch(void* const* d_in, const int* in_sizes, int n_in,
                              void* d_out, int out_size, void* d_ws, size_t ws_size,
                              hipStream_t stream) {
    const float* search = (const float*)d_in[0];
    const float* target = (const float*)d_in[1];
    const float* cls    = (const float*)d_in[2];
    const float* spos   = (const float*)d_in[3];
    const float* tpos   = (const float*)d_in[4];
    const float* ln1_g  = (const float*)d_in[5];
    const float* ln1_b  = (const float*)d_in[6];
    const float* Wq     = (const float*)d_in[7];
    const float* bq     = (const float*)d_in[8];
    const float* Wk     = (const float*)d_in[9];
    const float* bk     = (const float*)d_in[10];
    const float* Wv     = (const float*)d_in[11];
    const float* bv     = (const float*)d_in[12];
    const float* ln2_g  = (const float*)d_in[13];
    const float* ln2_b  = (const float*)d_in[14];
    const float* W1     = (const float*)d_in[15];
    const float* b1     = (const float*)d_in[16];
    const float* W2     = (const float*)d_in[17];
    const float* b2     = (const float*)d_in[18];
    const float* lnf_g  = (const float*)d_in[19];
    const float* lnf_b  = (const float*)d_in[20];
    const float* Wl1    = (const float*)d_in[21];
    const float* bl1    = (const float*)d_in[22];
    const float* Wl2    = (const float*)d_in[23];
    const float* bl2    = (const float*)d_in[24];

    size_t off = 0;
    char* base = (char*)d_ws;
    auto alloc = [&](size_t bytes) -> void* {
        void* p = base + off;
        off += (bytes + 255) & ~(size_t)255;
        return p;
    };

    bf16_t* xh = (bf16_t*)alloc((size_t)NROWS * DD * 2);
    bf16_t* xl = (bf16_t*)alloc((size_t)NROWS * DD * 2);
    float* ssum  = (float*)alloc((size_t)6*NROWS*4);
    float* ssum2 = (float*)alloc((size_t)6*NROWS*4);

    const int SQKV = 1152*DD;
    const int SM = DD*768;
    bf16_t* wqkvh = (bf16_t*)alloc((size_t)4*SQKV*2);
    bf16_t* wqkvl = (bf16_t*)alloc((size_t)4*SQKV*2);
    bf16_t* w1h = (bf16_t*)alloc((size_t)4*SM*2);
    bf16_t* w1l = (bf16_t*)alloc((size_t)4*SM*2);
    bf16_t* w2h = (bf16_t*)alloc((size_t)4*SM*2);
    bf16_t* w2l = (bf16_t*)alloc((size_t)4*SM*2);
    float* cqkv1 = (float*)alloc((size_t)4*1152*4);
    float* cqkv2 = (float*)alloc((size_t)4*1152*4);
    float* cm11  = (float*)alloc((size_t)4*768*4);
    float* cm12  = (float*)alloc((size_t)4*768*4);

    // union workspace: {q,k,vt-hi} aliases {midh,midl}; mid dominates.
    const size_t qB  = (size_t)NSEQ*DD*2;     // 553,728
    const size_t mB  = (size_t)NSEQ*768*2;    // 1,107,456
    const size_t perB = 2*mB;                 // >= 2*qB + vB
    size_t avail = (ws_size > off + 262144) ? (ws_size - off - 262144) : 0;
    int G = (int)(avail / perB);
    if (G > NBATCH) G = NBATCH;
    if (G < 1) G = 1;

    char* U = (char*)alloc(perB * G);
    bf16_t* qhB  = (bf16_t*)U;
    bf16_t* khB  = (bf16_t*)(U + qB*G);
    bf16_t* vth  = (bf16_t*)(U + 2*qB*G);
    bf16_t* midh = (bf16_t*)U;
    bf16_t* midl = (bf16_t*)(U + mB*G);

    build_x_kernel<<<(NROWS+3)/4, 256, 0, stream>>>(search, target, cls, spos, tpos,
                                                    xh, xl, ssum, ssum2);

    const int SQ = DD*DD;
    for (int l = 0; l < NLAYER; ++l) {
        bf16_t* dsth = wqkvh + (size_t)l*SQKV;
        bf16_t* dstl = wqkvl + (size_t)l*SQKV;
        transpose_split_kernel<<<(SQ+255)/256, 256, 0, stream>>>(Wq + (size_t)l*SQ, ln1_g + l*DD, dsth,          dstl,          DD, DD);
        transpose_split_kernel<<<(SQ+255)/256, 256, 0, stream>>>(Wk + (size_t)l*SQ, ln1_g + l*DD, dsth + 384*DD, dstl + 384*DD, DD, DD);
        transpose_split_kernel<<<(SQ+255)/256, 256, 0, stream>>>(Wv + (size_t)l*SQ, ln1_g + l*DD, dsth + 768*DD, dstl + 768*DD, DD, DD);
        transpose_split_kernel<<<(SM+255)/256, 256, 0, stream>>>(W1 + (size_t)l*SM, ln2_g + l*DD, w1h + (size_t)l*SM, w1l + (size_t)l*SM, DD, 768);
        transpose_split_kernel<<<(SM+255)/256, 256, 0, stream>>>(W2 + (size_t)l*SM, nullptr,      w2h + (size_t)l*SM, w2l + (size_t)l*SM, 768, DD);
    }
    colsum_kernel<<<dim3(2, NLAYER), 256, 0, stream>>>(Wq, ln1_g, ln1_b, bq, cqkv1, cqkv2, DD, DD, 1152, 0);
    colsum_kernel<<<dim3(2, NLAYER), 256, 0, stream>>>(Wk, ln1_g, ln1_b, bk, cqkv1, cqkv2, DD, DD, 1152, 384);
    colsum_kernel<<<dim3(2, NLAYER), 256, 0, stream>>>(Wv, ln1_g, ln1_b, bv, cqkv1, cqkv2, DD, DD, 1152, 768);
    colsum_kernel<<<dim3(3, NLAYER), 256, 0, stream>>>(W1, ln2_g, ln2_b, b1, cm11, cm12, DD, 768, 768, 0);

    for (int l = 0; l < NLAYER; ++l) {
        for (int b0 = 0; b0 < NBATCH; b0 += G) {
            int cb = (NBATCH - b0 < G) ? (NBATCH - b0) : G;
            int Mc = cb * NSEQ;
            bf16_t* xch = xh + (size_t)b0 * NSEQ * DD;
            bf16_t* xcl = xl + (size_t)b0 * NSEQ * DD;
            float* ssc  = ssum  + (size_t)b0 * NSEQ;
            float* ssc2 = ssum2 + (size_t)b0 * NSEQ;
            int mtiles = (Mc + 127)/128;
            int nwgQKV = 9*6*cb, nwgM1 = 6*mtiles, nwgM2 = 3*mtiles, nwgA = 12*cb;

            gemm_qkv<<<nwgQKV, 256, 0, stream>>>(xch,
                    wqkvh + (size_t)l*SQKV, wqkvl + (size_t)l*SQKV,
                    ssc, ssc2, cqkv1 + l*1152, cqkv2 + l*1152,
                    qhB, khB, vth, nwgQKV);
            attn_mfma<<<nwgA, 256, 0, stream>>>(qhB, khB, vth, xch, xcl,
                    ssc, ssc2, nwgA);
            gemm_m1<<<nwgM1, 256, 0, stream>>>(xch,
                    w1h + (size_t)l*SM, w1l + (size_t)l*SM,
                    ssc, ssc2, cm11 + l*768, cm12 + l*768,
                    midh, midl, Mc, nwgM1);
            gemm_m2<<<nwgM2, 256, 0, stream>>>(midh, midl,
                    w2h + (size_t)l*SM, w2l + (size_t)l*SM,
                    b2 + l*DD, xch, xcl, xch, xcl, ssc, ssc2, Mc, nwgM2);
        }
    }
    head_kernel<<<NBATCH, 384, 0, stream>>>(xh, xl, lnf_g, lnf_b, Wl1, bl1, Wl2, bl2, (float*)d_out);
}

// Round 17
// 3417.951 us; speedup vs baseline: 1.0755x; 1.0755x over previous
//
#include <hip/hip_runtime.h>
#include <hip/hip_bf16.h>
#include <math.h>

#define DD 384
#define NBATCH 64
#define NSEQ 721
#define NROWS (NBATCH*NSEQ)   // 46144
#define NLAYER 4
#define VTW 736               // padded token width for transposed V (mult of 8)

typedef __bf16 bf16_t;
typedef __bf16 bf16x8 __attribute__((ext_vector_type(8)));
typedef float  f32x4  __attribute__((ext_vector_type(4)));

static __device__ __forceinline__ void split_bf16(float v, bf16_t& h, bf16_t& l) {
    h = (bf16_t)v;
    l = (bf16_t)(v - (float)h);
}
static __device__ __forceinline__ bf16x8 bzero8() {
    bf16x8 v = {(bf16_t)0.f,(bf16_t)0.f,(bf16_t)0.f,(bf16_t)0.f,
                (bf16_t)0.f,(bf16_t)0.f,(bf16_t)0.f,(bf16_t)0.f};
    return v;
}
// async global->LDS, 16B per lane; LDS dest is wave-uniform base + lane*16,
// global source is PER-LANE.
static __device__ __forceinline__ void gload16(const void* g, void* l) {
    __builtin_amdgcn_global_load_lds(
        (const __attribute__((address_space(1))) unsigned int*)g,
        (__attribute__((address_space(3))) unsigned int*)l, 16, 0, 0);
}
// m204 bijective XCD swizzle
static __device__ __forceinline__ int xcd_swz(int nwg) {
    int orig = blockIdx.x;
    int q = nwg >> 3, r = nwg & 7;
    int xcd = orig & 7, within = orig >> 3;
    int base = (xcd < r) ? xcd*(q+1) : r*(q+1) + (xcd - r)*q;
    return base + within;
}
// reconstruct LN terms from 6 partial sums (slots stride NROWS)
static __device__ __forceinline__ void ln_from_partials(const float* ss, const float* ss2,
                                                        int row, float& mu, float& rstd) {
    float s = 0.f, q2 = 0.f;
    #pragma unroll
    for (int k = 0; k < 6; ++k) { s += ss[k*NROWS + row]; q2 += ss2[k*NROWS + row]; }
    mu = s * (1.f/DD);
    float var = q2 * (1.f/DD) - mu*mu;
    rstd = rsqrtf(var + 1e-5f);
}

// ---------------------------------------------------------------- build x (split residual + ln1 stats)
__global__ __launch_bounds__(256) void build_x_kernel(const float* __restrict__ search,
                               const float* __restrict__ target,
                               const float* __restrict__ cls,
                               const float* __restrict__ spos,
                               const float* __restrict__ tpos,
                               bf16_t* __restrict__ xh, bf16_t* __restrict__ xl,
                               float* __restrict__ wss, float* __restrict__ wss2) {
    int wave = threadIdx.x >> 6, lane = threadIdx.x & 63;
    int row = blockIdx.x * 4 + wave;
    if (row >= NROWS) return;
    int b = row / NSEQ, n = row % NSEQ;
    float s = 0.f, q2 = 0.f;
    #pragma unroll
    for (int i = 0; i < 6; ++i) {
        int d = lane + 64*i;
        float val;
        if (n == 0)        val = cls[d];
        else if (n <= 576) val = search[((size_t)b*576 + (n-1))*DD + d] + spos[(size_t)(n-1)*DD + d];
        else               val = target[((size_t)b*144 + (n-577))*DD + d] + tpos[(size_t)(n-577)*DD + d];
        bf16_t h, l;
        split_bf16(val, h, l);
        xh[(size_t)row*DD + d] = h;
        xl[(size_t)row*DD + d] = l;
        s += val; q2 += val*val;
    }
    #pragma unroll
    for (int m = 1; m < 64; m <<= 1) { s += __shfl_xor(s, m); q2 += __shfl_xor(q2, m); }
    if (lane == 0) {
        wss[row] = s; wss2[row] = q2;
        #pragma unroll
        for (int k = 1; k < 6; ++k) { wss[k*NROWS + row] = 0.f; wss2[k*NROWS + row] = 0.f; }
    }
}

// ---------------------------------------------------------------- weight prep
__global__ void transpose_split_kernel(const float* __restrict__ src,
                                       const float* __restrict__ g,
                                       bf16_t* __restrict__ dh,
                                       bf16_t* __restrict__ dl,
                                       int K, int N) {
    int idx = blockIdx.x * blockDim.x + threadIdx.x;
    if (idx >= K*N) return;
    int k = idx / N, n = idx % N;
    float v = src[idx];
    if (g) v *= g[k];
    bf16_t h, l;
    split_bf16(v, h, l);
    dh[(size_t)n*K + k] = h;
    dl[(size_t)n*K + k] = l;
}

// colsums for LN-fold
__global__ void colsum_kernel(const float* __restrict__ W, const float* __restrict__ g,
                              const float* __restrict__ b, const float* __restrict__ bias,
                              float* __restrict__ c1, float* __restrict__ c2,
                              int K, int N, int outStride, int outOff) {
    int l = blockIdx.y;
    int n = blockIdx.x * 256 + threadIdx.x;
    if (n >= N) return;
    const float* Wl = W + (size_t)l*K*N;
    const float* gl = g + (size_t)l*K;
    const float* bl = b + (size_t)l*K;
    float s1 = 0.f, s2 = 0.f;
    for (int k = 0; k < K; ++k) {
        float w = Wl[(size_t)k*N + n];
        s1 = fmaf(gl[k], w, s1);
        s2 = fmaf(bl[k], w, s2);
    }
    c1[(size_t)l*outStride + outOff + n] = s1;
    c2[(size_t)l*outStride + outOff + n] = s2 + bias[(size_t)l*N + n];
}

// ---------------------------------------------------------------- GEMM cores
// core3: 3-pass split (AhBh + AhBl + AlBh), 32 slots / 32KB staging.
static __device__ __forceinline__ void gemm_core3(
        const bf16_t* __restrict__ ah, const bf16_t* __restrict__ al,
        const bf16_t* __restrict__ bh, const bf16_t* __restrict__ bl,
        bf16_t (&ls)[32][64][8],
        int m0, int n0, int K, f32x4 (&acc)[4][4]) {
    int t = threadIdx.x;
    int w = t >> 6, lane = t & 63;
    int c = lane & 15, g = lane >> 4;
    int wr = w >> 1, wc = w & 1;
    const bf16_t* src0 = (w==0) ? ah : (w==1) ? al : (w==2) ? bh : bl;
    int base_rc = (w < 2) ? m0 : n0;
    const bf16_t* srcbase = src0 + (size_t)(base_rc + c)*K + 8*g;

    int ksteps = K >> 5;
    for (int kt = 0; kt < ksteps; ++kt) {
        int k0 = kt << 5;
        __syncthreads();
        #pragma unroll
        for (int i = 0; i < 8; ++i)
            gload16(srcbase + (size_t)(16*i)*K + k0, &ls[w*8 + i][0][0]);
        __syncthreads();
        bf16x8 af_h[4], af_l[4], bf_h[4], bf_l[4];
        #pragma unroll
        for (int i = 0; i < 4; ++i) {
            af_h[i] = *(const bf16x8*)&ls[     4*wr + i][lane][0];
            af_l[i] = *(const bf16x8*)&ls[ 8 + 4*wr + i][lane][0];
            bf_h[i] = *(const bf16x8*)&ls[16 + 4*wc + i][lane][0];
            bf_l[i] = *(const bf16x8*)&ls[24 + 4*wc + i][lane][0];
        }
        #pragma unroll
        for (int i = 0; i < 4; ++i)
            #pragma unroll
            for (int j = 0; j < 4; ++j) {
                acc[i][j] = __builtin_amdgcn_mfma_f32_16x16x32_bf16(af_h[i], bf_h[j], acc[i][j], 0,0,0);
                acc[i][j] = __builtin_amdgcn_mfma_f32_16x16x32_bf16(af_h[i], bf_l[j], acc[i][j], 0,0,0);
                acc[i][j] = __builtin_amdgcn_mfma_f32_16x16x32_bf16(af_l[i], bf_h[j], acc[i][j], 0,0,0);
            }
    }
}

// core2: 2-pass (A single bf16; B hi/lo exact) = A@(Bh+Bl). 24 slots staged
// (slots 0-7 A, 8-15 Bh, 16-23 Bl), 6 loads/wave/step, 32 MFMA/step.
static __device__ __forceinline__ void gemm_core2(
        const bf16_t* __restrict__ ah,
        const bf16_t* __restrict__ bh, const bf16_t* __restrict__ bl,
        bf16_t (&ls)[32][64][8],
        int m0, int n0, int K, f32x4 (&acc)[4][4]) {
    int t = threadIdx.x;
    int w = t >> 6, lane = t & 63;
    int c = lane & 15, g = lane >> 4;
    int wr = w >> 1, wc = w & 1;

    int ksteps = K >> 5;
    for (int kt = 0; kt < ksteps; ++kt) {
        int k0 = kt << 5;
        __syncthreads();
        #pragma unroll
        for (int i = 0; i < 6; ++i) {
            int s = w*6 + i;                         // wave-uniform slot id
            const bf16_t* src = (s < 8) ? ah : (s < 16) ? bh : bl;
            int base = (s < 8) ? m0 : n0;
            int row = base + (s & 7)*16 + c;
            gload16(src + (size_t)row*K + k0 + 8*g, &ls[s][0][0]);
        }
        __syncthreads();
        bf16x8 af[4], bfh[4], bfl[4];
        #pragma unroll
        for (int i = 0; i < 4; ++i) {
            af[i]  = *(const bf16x8*)&ls[     4*wr + i][lane][0];
            bfh[i] = *(const bf16x8*)&ls[ 8 + 4*wc + i][lane][0];
            bfl[i] = *(const bf16x8*)&ls[16 + 4*wc + i][lane][0];
        }
        #pragma unroll
        for (int i = 0; i < 4; ++i)
            #pragma unroll
            for (int j = 0; j < 4; ++j) {
                acc[i][j] = __builtin_amdgcn_mfma_f32_16x16x32_bf16(af[i], bfh[j], acc[i][j], 0,0,0);
                acc[i][j] = __builtin_amdgcn_mfma_f32_16x16x32_bf16(af[i], bfl[j], acc[i][j], 0,0,0);
            }
    }
}

// ---------------------------------------------------------------- fused QKV GEMM (LN-folded, 2-pass)
// Batch-aligned m-tiles (6/batch). Outputs coalesced via in-LDS regroup.
// V pad tokens forced to ZERO (NaN-garbage would poison PV; round-11 lesson).
__global__ __launch_bounds__(256, 4) void gemm_qkv(
        const bf16_t* __restrict__ ah,
        const bf16_t* __restrict__ bh, const bf16_t* __restrict__ bl,
        const float* __restrict__ ss, const float* __restrict__ ss2,
        const float* __restrict__ c1, const float* __restrict__ c2,
        bf16_t* __restrict__ qout, bf16_t* __restrict__ kout,
        bf16_t* __restrict__ vth,
        int nwg) {
    __shared__ __align__(16) bf16_t ls[32][64][8];
    int wgid = xcd_swz(nwg);
    int mt = wgid / 9, n0 = (wgid % 9) * 128;
    int blb = mt / 6;
    int tok_base = (mt % 6) * 128;
    int m0d = blb*NSEQ + tok_base;           // contiguous data rows (tail reads spill, discarded)
    f32x4 zero4 = {0.f,0.f,0.f,0.f};
    f32x4 acc[4][4];
    #pragma unroll
    for (int i = 0; i < 4; ++i)
        #pragma unroll
        for (int j = 0; j < 4; ++j) acc[i][j] = zero4;
    gemm_core2(ah, bh, bl, ls, m0d, n0, DD, acc);

    int t = threadIdx.x, w = t >> 6, lane = t & 63;
    int c = lane & 15, g = lane >> 4;
    int wr = w >> 1, wc = w & 1;
    // hoisted per-row LN terms (valid tokens only)
    float rmu[16], rrs[16];
    #pragma unroll
    for (int i = 0; i < 4; ++i)
        #pragma unroll
        for (int r = 0; r < 4; ++r) {
            int tok = tok_base + 64*wr + 16*i + 4*g + r;
            float mu = 0.f, rstd = 1.f;
            if (tok < NSEQ) ln_from_partials(ss, ss2, blb*NSEQ + tok, mu, rstd);
            rmu[i*4+r] = mu; rrs[i*4+r] = rstd;
        }
    int seg = n0 / 384;                      // 0=Q 1=K 2=V
    bf16_t* LST = &ls[0][0][0];              // 128x128 bf16 regroup buffer (32KB)
    if (seg < 2) {
        bf16_t* outb = (seg == 0) ? qout : kout;
        int segoff = seg * 384;
        __syncthreads();                     // core done reading ls
        #pragma unroll
        for (int j = 0; j < 4; ++j) {
            int nl = 64*wc + 16*j + c;       // tile-local n 0..127
            float C1 = c1[n0 + nl], C2 = c2[n0 + nl];
            #pragma unroll
            for (int i = 0; i < 4; ++i)
                #pragma unroll
                for (int r = 0; r < 4; ++r) {
                    int rl = 64*wr + 16*i + 4*g + r;   // tile-local row 0..127
                    float val = rrs[i*4+r]*(acc[i][j][r] - rmu[i*4+r]*C1) + C2;
                    LST[rl*128 + (nl ^ ((rl & 15) << 3))] = (bf16_t)val;
                }
        }
        __syncthreads();
        #pragma unroll
        for (int p = 0; p < 8; ++p) {
            int chunk = t + 256*p;
            int rl = chunk >> 4;
            int nl0 = (chunk & 15) * 8;
            int tok = tok_base + rl;
            if (tok >= NSEQ) continue;
            uint4 v = *(const uint4*)&LST[rl*128 + (nl0 ^ ((rl & 15) << 3))];
            *(uint4*)(outb + (size_t)(blb*NSEQ + tok)*DD + (n0 - segoff) + nl0) = v;
        }
    } else {
        int vbase = n0 - 768;                // 0 / 128 / 256
        __syncthreads();                     // core done reading ls
        #pragma unroll
        for (int j = 0; j < 4; ++j) {
            int d = 64*wc + 16*j + c;
            float C1 = c1[n0 + d], C2 = c2[n0 + d];
            #pragma unroll
            for (int i = 0; i < 4; ++i)
                #pragma unroll
                for (int r = 0; r < 4; ++r) {
                    int tokl = 64*wr + 16*i + 4*g + r;   // local 0..127
                    float val = rrs[i*4+r]*(acc[i][j][r] - rmu[i*4+r]*C1) + C2;
                    if (tok_base + tokl >= NSEQ) val = 0.f;   // kill NaN garbage in pad
                    LST[d*128 + (tokl ^ ((d & 15) << 3))] = (bf16_t)val;
                }
        }
        __syncthreads();
        #pragma unroll
        for (int p = 0; p < 8; ++p) {
            int chunk = t + 256*p;
            int d = chunk >> 4;
            int tok0 = (chunk & 15) * 8;
            int tg = tok_base + tok0;
            if (tg + 8 > VTW) continue;      // don't spill into next d-row
            uint4 v = *(const uint4*)&LST[d*128 + (tok0 ^ ((d & 15) << 3))];
            *(uint4*)(vth + ((size_t)(blb*DD + vbase + d))*VTW + tg) = v;
        }
    }
}

// ---------------------------------------------------------------- M1: LN-folded gelu GEMM (2-pass A)
// out hi/lo [M][768], immediate scalar stores (NO acc parking -> no spill;
// round-16 lesson: parking val in acc across LST drains spilled 230MB).
__global__ __launch_bounds__(256, 4) void gemm_m1(
        const bf16_t* __restrict__ ah,
        const bf16_t* __restrict__ bh, const bf16_t* __restrict__ bl,
        const float* __restrict__ ss, const float* __restrict__ ss2,
        const float* __restrict__ c1, const float* __restrict__ c2,
        bf16_t* __restrict__ o1, bf16_t* __restrict__ o2,
        int M, int nwg) {
    __shared__ __align__(16) bf16_t ls[32][64][8];
    int wgid = xcd_swz(nwg);
    int m0 = (wgid / 6) * 128, n0 = (wgid % 6) * 128;
    f32x4 zero4 = {0.f,0.f,0.f,0.f};
    f32x4 acc[4][4];
    #pragma unroll
    for (int i = 0; i < 4; ++i)
        #pragma unroll
        for (int j = 0; j < 4; ++j) acc[i][j] = zero4;
    gemm_core2(ah, bh, bl, ls, m0, n0, DD, acc);

    int t = threadIdx.x, w = t >> 6, lane = t & 63;
    int c = lane & 15, g = lane >> 4;
    int wr = w >> 1, wc = w & 1;
    float rmu[16], rrs[16];
    #pragma unroll
    for (int i = 0; i < 4; ++i)
        #pragma unroll
        for (int r = 0; r < 4; ++r) {
            int row = m0 + 64*wr + 16*i + 4*g + r;
            float mu = 0.f, rstd = 1.f;
            if (row < M) ln_from_partials(ss, ss2, row, mu, rstd);
            rmu[i*4+r] = mu; rrs[i*4+r] = rstd;
        }
    #pragma unroll
    for (int j = 0; j < 4; ++j) {
        int n = n0 + 64*wc + 16*j + c;
        float C1 = c1[n], C2 = c2[n];
        #pragma unroll
        for (int i = 0; i < 4; ++i) {
            int rbase = m0 + 64*wr + 16*i + 4*g;
            #pragma unroll
            for (int r = 0; r < 4; ++r) {
                int row = rbase + r;
                if (row >= M) continue;
                float val = rrs[i*4+r]*(acc[i][j][r] - rmu[i*4+r]*C1) + C2;
                val = 0.5f*val*(1.0f + erff(val*0.70710678118654752f));
                bf16_t h, l;
                split_bf16(val, h, l);
                size_t o = (size_t)row*768 + n;
                o1[o] = h;
                o2[o] = l;
            }
        }
    }
}

// ---------------------------------------------------------------- M2: residual-update GEMM (3-pass)
// x += mid@W2 + b2; split residual hi/lo scalar stores + ln2-stat partials
// (round-15 proven epilogue; no acc parking).
__global__ __launch_bounds__(256, 4) void gemm_m2(
        const bf16_t* __restrict__ ah, const bf16_t* __restrict__ al,
        const bf16_t* __restrict__ bh, const bf16_t* __restrict__ bl,
        const float* __restrict__ bias,
        const bf16_t* __restrict__ resh, const bf16_t* __restrict__ resl,
        bf16_t* __restrict__ o1, bf16_t* __restrict__ o2,
        float* __restrict__ wss, float* __restrict__ wss2,
        int M, int nwg) {
    __shared__ __align__(16) bf16_t ls[32][64][8];
    int wgid = xcd_swz(nwg);
    int m0 = (wgid / 3) * 128, n0 = (wgid % 3) * 128;
    f32x4 zero4 = {0.f,0.f,0.f,0.f};
    f32x4 acc[4][4];
    #pragma unroll
    for (int i = 0; i < 4; ++i)
        #pragma unroll
        for (int j = 0; j < 4; ++j) acc[i][j] = zero4;
    gemm_core3(ah, al, bh, bl, ls, m0, n0, 768, acc);

    int t = threadIdx.x, w = t >> 6, lane = t & 63;
    int c = lane & 15, g = lane >> 4;
    int wr = w >> 1, wc = w & 1;
    int slot = (wgid % 3) + 3*wc;            // stat slots 0..5
    #pragma unroll
    for (int i = 0; i < 4; ++i)
        #pragma unroll
        for (int r = 0; r < 4; ++r) {
            int row = m0 + 64*wr + 16*i + 4*g + r;
            if (row >= M) continue;
            float s = 0.f, q2 = 0.f;
            #pragma unroll
            for (int j = 0; j < 4; ++j) {
                int n = n0 + 64*wc + 16*j + c;
                size_t o = (size_t)row*DD + n;
                float val = acc[i][j][r] + bias[n] + (float)resh[o] + (float)resl[o];
                bf16_t h, l;
                split_bf16(val, h, l);
                o1[o] = h;
                o2[o] = l;
                s += val; q2 += val*val;
            }
            #pragma unroll
            for (int m = 1; m < 16; m <<= 1) { s += __shfl_xor(s, m); q2 += __shfl_xor(q2, m); }
            if (c == 0) {
                wss[slot*NROWS + row] = s;
                wss2[slot*NROWS + row] = q2;
            }
        }
}

// ---------------------------------------------------------------- MFMA attention
// 4 waves / 64 q-rows; K + V-hi DMA-staged (48KB LDS). __launch_bounds__(256,2)
// pins 2 blk/CU (proven L2-friendly residency; rounds 12-15 A/B).
// PV 2-pass Vh*(Ph+Pl); defer-max (T13).
__global__ __launch_bounds__(256, 2) void attn_mfma(
        const bf16_t* __restrict__ qh, const bf16_t* __restrict__ kh,
        const bf16_t* __restrict__ vth,
        bf16_t* __restrict__ xh, bf16_t* __restrict__ xl,
        float* __restrict__ wss, float* __restrict__ wss2, int nwg) {
    __shared__ __align__(16) char smem[49152];
    bf16_t* kf = (bf16_t*)smem;              // 24 slots x 1KB  (K tile)
    char* vhp = smem + 24576;                // 24KB V-hi

    int t = threadIdx.x, w = t >> 6, lane = t & 63;
    int c = lane & 15, g = lane >> 4;
    int wgid = xcd_swz(nwg);
    int bl_ = wgid / 12;
    int q0 = (wgid % 12) * 64;
    size_t bb = (size_t)bl_ * NSEQ;
    int qrow = q0 + 16*w + c;
    bool qok = (qrow < NSEQ);
    const float scale = 0.05103103630798287f;   // 384^-0.5
    int vswz = (c ^ (c >> 2)) & 3;              // PV read slot swizzle
    int dma_dd  = lane >> 2;                    // V DMA lane mapping
    int dma_kv8 = (lane & 3) ^ ((dma_dd ^ (dma_dd >> 2)) & 3);

    bf16x8 qf[12];
    #pragma unroll
    for (int ks = 0; ks < 12; ++ks) {
        if (qok) qf[ks] = *(const bf16x8*)(qh + (bb + qrow)*DD + 32*ks + 8*g);
        else     qf[ks] = bzero8();
    }

    f32x4 zero4 = {0.f,0.f,0.f,0.f};
    f32x4 oacc[24];
    #pragma unroll
    for (int i = 0; i < 24; ++i) oacc[i] = zero4;
    float m_run = -1e30f, l_run = 0.f;

    // prologue: issue K(0)
    #pragma unroll
    for (int i = 0; i < 6; ++i) {
        int s = i*4 + w;
        int ks = s >> 1, mf = s & 1;
        gload16(kh + (bb + (size_t)(16*mf + c))*DD + 32*ks + 8*g, kf + s*512);
    }

    for (int kt = 0; kt < 23; ++kt) {
        int kv0 = kt * 32;
        asm volatile("s_waitcnt vmcnt(0)" ::: "memory");   // K(kt) landed
        __builtin_amdgcn_s_barrier();
        // issue V(kt): flight hides under QK+softmax
        #pragma unroll
        for (int i = 0; i < 6; ++i) {
            int s = i*4 + w;
            size_t gro = ((size_t)(bl_*DD + 16*s + dma_dd))*VTW + kv0 + 8*dma_kv8;
            gload16(vth + gro, (bf16_t*)vhp + s*512);
        }
        // ---- QK: S^T = K * Q^T
        f32x4 sacc[2];
        sacc[0] = zero4; sacc[1] = zero4;
        #pragma unroll
        for (int ks = 0; ks < 12; ++ks) {
            bf16x8 a0 = *(const bf16x8*)(kf + ((size_t)(2*ks+0)*64 + lane)*8);
            bf16x8 a1 = *(const bf16x8*)(kf + ((size_t)(2*ks+1)*64 + lane)*8);
            sacc[0] = __builtin_amdgcn_mfma_f32_16x16x32_bf16(a0, qf[ks], sacc[0], 0,0,0);
            sacc[1] = __builtin_amdgcn_mfma_f32_16x16x32_bf16(a1, qf[ks], sacc[1], 0,0,0);
        }
        // ---- online softmax with defer-max
        float p[2][4];
        float mx = -1e30f;
        #pragma unroll
        for (int mf = 0; mf < 2; ++mf)
            #pragma unroll
            for (int r = 0; r < 4; ++r) {
                float sv = sacc[mf][r] * scale;
                int kv = kv0 + 16*mf + 4*g + r;
                if (kv >= NSEQ) sv = -1e30f;
                p[mf][r] = sv;
                mx = fmaxf(mx, sv);
            }
        mx = fmaxf(mx, __shfl_xor(mx, 16));
        mx = fmaxf(mx, __shfl_xor(mx, 32));
        bool skip = __all(mx <= m_run + 8.f);   // P bounded by e^8: safe in f32
        float m_new = skip ? m_run : fmaxf(m_run, mx);
        float psum = 0.f;
        #pragma unroll
        for (int mf = 0; mf < 2; ++mf)
            #pragma unroll
            for (int r = 0; r < 4; ++r) {
                float pv = __expf(p[mf][r] - m_new);
                p[mf][r] = pv;
                psum += pv;
            }
        psum += __shfl_xor(psum, 16);
        psum += __shfl_xor(psum, 32);
        if (!skip) {
            float corr = __expf(m_run - m_new);
            l_run = l_run * corr + psum;
            #pragma unroll
            for (int i = 0; i < 24; ++i) oacc[i] *= corr;
            m_run = m_new;
        } else {
            l_run += psum;
        }
        bf16x8 ph, pl;
        #pragma unroll
        for (int mf = 0; mf < 2; ++mf)
            #pragma unroll
            for (int r = 0; r < 4; ++r) {
                bf16_t hh, ll;
                split_bf16(p[mf][r], hh, ll);
                ph[mf*4 + r] = hh;
                pl[mf*4 + r] = ll;
            }
        asm volatile("s_waitcnt vmcnt(0)" ::: "memory");   // V(kt) landed
        __builtin_amdgcn_s_barrier();
        // issue K(kt+1): flight hides under PV
        if (kt + 1 < 23) {
            int kv0n = kv0 + 32;
            #pragma unroll
            for (int i = 0; i < 6; ++i) {
                int s = i*4 + w;
                int ks = s >> 1, mf = s & 1;
                gload16(kh + (bb + (size_t)(kv0n + 16*mf + c))*DD + 32*ks + 8*g, kf + s*512);
            }
        }
        // ---- PV: O^T += Vh^T * (Ph + Pl)  (2-pass)
        #pragma unroll
        for (int mf = 0; mf < 24; ++mf) {
            int dr = 16*mf + c;
            const char* vb = vhp + dr*64;
            int o0 = ((((g>>1)     ^ vswz) << 4) | (8*(g&1)));
            int o1 = (((2 + (g>>1)) ^ vswz) << 4) | (8*(g&1));
            union { uint2 u[2]; bf16x8 v; } va;
            va.u[0] = *(const uint2*)(vb + o0);
            va.u[1] = *(const uint2*)(vb + o1);
            oacc[mf] = __builtin_amdgcn_mfma_f32_16x16x32_bf16(va.v, ph, oacc[mf], 0,0,0);
            oacc[mf] = __builtin_amdgcn_mfma_f32_16x16x32_bf16(va.v, pl, oacc[mf], 0,0,0);
        }
    }
    float inv = 1.f / l_run;
    float s = 0.f, q2 = 0.f;
    if (qok) {
        bf16_t* xhr = xh + (bb + qrow)*DD;
        bf16_t* xlr = xl + (bb + qrow)*DD;
        #pragma unroll
        for (int mf = 0; mf < 24; ++mf)
            #pragma unroll
            for (int r = 0; r < 4; ++r) {
                int d = 16*mf + 4*g + r;
                float xv = (float)xhr[d] + (float)xlr[d] + oacc[mf][r]*inv;
                bf16_t h, l;
                split_bf16(xv, h, l);
                xhr[d] = h;
                xlr[d] = l;
                s += xv; q2 += xv*xv;
            }
    }
    s += __shfl_xor(s, 16);  q2 += __shfl_xor(q2, 16);
    s += __shfl_xor(s, 32);  q2 += __shfl_xor(q2, 32);
    if (qok && g == 0) {
        int rowL = bl_*NSEQ + qrow;
        wss[rowL] = s; wss2[rowL] = q2;
        #pragma unroll
        for (int k = 1; k < 6; ++k) { wss[k*NROWS + rowL] = 0.f; wss2[k*NROWS + rowL] = 0.f; }
    }
}

// ---------------------------------------------------------------- head (f32)
__global__ __launch_bounds__(384) void head_kernel(const bf16_t* __restrict__ xh,
    const bf16_t* __restrict__ xl,
    const float* __restrict__ g, const float* __restrict__ bb,
    const float* __restrict__ Wl1, const float* __restrict__ bl1,
    const float* __restrict__ Wl2, const float* __restrict__ bl2,
    float* __restrict__ outp) {
    __shared__ float yv[384];
    __shared__ float r1[6], r2[6], r3[6];
    int b = blockIdx.x, t = threadIdx.x;
    size_t o = (size_t)b*NSEQ*DD + t;
    float v = (float)xh[o] + (float)xl[o];
    float s = v;
    #pragma unroll
    for (int m = 1; m < 64; m <<= 1) s += __shfl_xor(s, m);
    if ((t & 63) == 0) r1[t>>6] = s;
    __syncthreads();
    float mu = (r1[0]+r1[1]+r1[2]+r1[3]+r1[4]+r1[5]) * (1.f/384.f);
    float dd = v - mu;
    float sq = dd*dd;
    #pragma unroll
    for (int m = 1; m < 64; m <<= 1) sq += __shfl_xor(sq, m);
    if ((t & 63) == 0) r2[t>>6] = sq;
    __syncthreads();
    float var = (r2[0]+r2[1]+r2[2]+r2[3]+r2[4]+r2[5]) * (1.f/384.f);
    float rstd = rsqrtf(var + 1e-5f);
    yv[t] = dd*rstd*g[t] + bb[t];
    __syncthreads();
    float acc = bl1[t];
    for (int d2 = 0; d2 < 384; d2++) acc = fmaf(yv[d2], Wl1[d2*384 + t], acc);
    acc = fmaxf(acc, 0.f);
    float oo = acc * Wl2[t];
    #pragma unroll
    for (int m = 1; m < 64; m <<= 1) oo += __shfl_xor(oo, m);
    if ((t & 63) == 0) r3[t>>6] = oo;
    __syncthreads();
    if (t == 0) outp[b] = r3[0]+r3[1]+r3[2]+r3[3]+r3[4]+r3[5] + bl2[0];
}

// ---------------------------------------------------------------- launch
extern "C" void kernel_launch(void* const* d_in, const int* in_sizes, int n_in,
                              void* d_out, int out_size, void* d_ws, size_t ws_size,
                              hipStream_t stream) {
    const float* search = (const float*)d_in[0];
    const float* target = (const float*)d_in[1];
    const float* cls    = (const float*)d_in[2];
    const float* spos   = (const float*)d_in[3];
    const float* tpos   = (const float*)d_in[4];
    const float* ln1_g  = (const float*)d_in[5];
    const float* ln1_b  = (const float*)d_in[6];
    const float* Wq     = (const float*)d_in[7];
    const float* bq     = (const float*)d_in[8];
    const float* Wk     = (const float*)d_in[9];
    const float* bk     = (const float*)d_in[10];
    const float* Wv     = (const float*)d_in[11];
    const float* bv     = (const float*)d_in[12];
    const float* ln2_g  = (const float*)d_in[13];
    const float* ln2_b  = (const float*)d_in[14];
    const float* W1     = (const float*)d_in[15];
    const float* b1     = (const float*)d_in[16];
    const float* W2     = (const float*)d_in[17];
    const float* b2     = (const float*)d_in[18];
    const float* lnf_g  = (const float*)d_in[19];
    const float* lnf_b  = (const float*)d_in[20];
    const float* Wl1    = (const float*)d_in[21];
    const float* bl1    = (const float*)d_in[22];
    const float* Wl2    = (const float*)d_in[23];
    const float* bl2    = (const float*)d_in[24];

    size_t off = 0;
    char* base = (char*)d_ws;
    auto alloc = [&](size_t bytes) -> void* {
        void* p = base + off;
        off += (bytes + 255) & ~(size_t)255;
        return p;
    };

    bf16_t* xh = (bf16_t*)alloc((size_t)NROWS * DD * 2);
    bf16_t* xl = (bf16_t*)alloc((size_t)NROWS * DD * 2);
    float* ssum  = (float*)alloc((size_t)6*NROWS*4);
    float* ssum2 = (float*)alloc((size_t)6*NROWS*4);

    const int SQKV = 1152*DD;
    const int SM = DD*768;
    bf16_t* wqkvh = (bf16_t*)alloc((size_t)4*SQKV*2);
    bf16_t* wqkvl = (bf16_t*)alloc((size_t)4*SQKV*2);
    bf16_t* w1h = (bf16_t*)alloc((size_t)4*SM*2);
    bf16_t* w1l = (bf16_t*)alloc((size_t)4*SM*2);
    bf16_t* w2h = (bf16_t*)alloc((size_t)4*SM*2);
    bf16_t* w2l = (bf16_t*)alloc((size_t)4*SM*2);
    float* cqkv1 = (float*)alloc((size_t)4*1152*4);
    float* cqkv2 = (float*)alloc((size_t)4*1152*4);
    float* cm11  = (float*)alloc((size_t)4*768*4);
    float* cm12  = (float*)alloc((size_t)4*768*4);

    // union workspace: {q,k,vt-hi} aliases {midh,midl}; mid dominates.
    const size_t qB  = (size_t)NSEQ*DD*2;     // 553,728
    const size_t mB  = (size_t)NSEQ*768*2;    // 1,107,456
    const size_t perB = 2*mB;                 // >= 2*qB + vB
    size_t avail = (ws_size > off + 262144) ? (ws_size - off - 262144) : 0;
    int G = (int)(avail / perB);
    if (G > NBATCH) G = NBATCH;
    if (G < 1) G = 1;

    char* U = (char*)alloc(perB * G);
    bf16_t* qhB  = (bf16_t*)U;
    bf16_t* khB  = (bf16_t*)(U + qB*G);
    bf16_t* vth  = (bf16_t*)(U + 2*qB*G);
    bf16_t* midh = (bf16_t*)U;
    bf16_t* midl = (bf16_t*)(U + mB*G);

    build_x_kernel<<<(NROWS+3)/4, 256, 0, stream>>>(search, target, cls, spos, tpos,
                                                    xh, xl, ssum, ssum2);

    const int SQ = DD*DD;
    for (int l = 0; l < NLAYER; ++l) {
        bf16_t* dsth = wqkvh + (size_t)l*SQKV;
        bf16_t* dstl = wqkvl + (size_t)l*SQKV;
        transpose_split_kernel<<<(SQ+255)/256, 256, 0, stream>>>(Wq + (size_t)l*SQ, ln1_g + l*DD, dsth,          dstl,          DD, DD);
        transpose_split_kernel<<<(SQ+255)/256, 256, 0, stream>>>(Wk + (size_t)l*SQ, ln1_g + l*DD, dsth + 384*DD, dstl + 384*DD, DD, DD);
        transpose_split_kernel<<<(SQ+255)/256, 256, 0, stream>>>(Wv + (size_t)l*SQ, ln1_g + l*DD, dsth + 768*DD, dstl + 768*DD, DD, DD);
        transpose_split_kernel<<<(SM+255)/256, 256, 0, stream>>>(W1 + (size_t)l*SM, ln2_g + l*DD, w1h + (size_t)l*SM, w1l + (size_t)l*SM, DD, 768);
        transpose_split_kernel<<<(SM+255)/256, 256, 0, stream>>>(W2 + (size_t)l*SM, nullptr,      w2h + (size_t)l*SM, w2l + (size_t)l*SM, 768, DD);
    }
    colsum_kernel<<<dim3(2, NLAYER), 256, 0, stream>>>(Wq, ln1_g, ln1_b, bq, cqkv1, cqkv2, DD, DD, 1152, 0);
    colsum_kernel<<<dim3(2, NLAYER), 256, 0, stream>>>(Wk, ln1_g, ln1_b, bk, cqkv1, cqkv2, DD, DD, 1152, 384);
    colsum_kernel<<<dim3(2, NLAYER), 256, 0, stream>>>(Wv, ln1_g, ln1_b, bv, cqkv1, cqkv2, DD, DD, 1152, 768);
    colsum_kernel<<<dim3(3, NLAYER), 256, 0, stream>>>(W1, ln2_g, ln2_b, b1, cm11, cm12, DD, 768, 768, 0);

    for (int l = 0; l < NLAYER; ++l) {
        for (int b0 = 0; b0 < NBATCH; b0 += G) {
            int cb = (NBATCH - b0 < G) ? (NBATCH - b0) : G;
            int Mc = cb * NSEQ;
            bf16_t* xch = xh + (size_t)b0 * NSEQ * DD;
            bf16_t* xcl = xl + (size_t)b0 * NSEQ * DD;
            float* ssc  = ssum  + (size_t)b0 * NSEQ;
            float* ssc2 = ssum2 + (size_t)b0 * NSEQ;
            int mtiles = (Mc + 127)/128;
            int nwgQKV = 9*6*cb, nwgM1 = 6*mtiles, nwgM2 = 3*mtiles, nwgA = 12*cb;

            gemm_qkv<<<nwgQKV, 256, 0, stream>>>(xch,
                    wqkvh + (size_t)l*SQKV, wqkvl + (size_t)l*SQKV,
                    ssc, ssc2, cqkv1 + l*1152, cqkv2 + l*1152,
                    qhB, khB, vth, nwgQKV);
            attn_mfma<<<nwgA, 256, 0, stream>>>(qhB, khB, vth, xch, xcl,
                    ssc, ssc2, nwgA);
            gemm_m1<<<nwgM1, 256, 0, stream>>>(xch,
                    w1h + (size_t)l*SM, w1l + (size_t)l*SM,
                    ssc, ssc2, cm11 + l*768, cm12 + l*768,
                    midh, midl, Mc, nwgM1);
            gemm_m2<<<nwgM2, 256, 0, stream>>>(midh, midl,
                    w2h + (size_t)l*SM, w2l + (size_t)l*SM,
                    b2 + l*DD, xch, xcl, xch, xcl, ssc, ssc2, Mc, nwgM2);
        }
    }
    head_kernel<<<NBATCH, 384, 0, stream>>>(xh, xl, lnf_g, lnf_b, Wl1, bl1, Wl2, bl2, (float*)d_out);
}

// Round 18
// 3234.226 us; speedup vs baseline: 1.1366x; 1.0568x over previous
//
#include <hip/hip_runtime.h>
#include <hip/hip_bf16.h>
#include <math.h>

#define DD 384
#define NBATCH 64
#define NSEQ 721
#define NROWS (NBATCH*NSEQ)   // 46144
#define NLAYER 4
#define VTW 736               // padded token width for transposed V (mult of 8)

typedef __bf16 bf16_t;
typedef __bf16 bf16x8 __attribute__((ext_vector_type(8)));
typedef float  f32x4  __attribute__((ext_vector_type(4)));

static __device__ __forceinline__ void split_bf16(float v, bf16_t& h, bf16_t& l) {
    h = (bf16_t)v;
    l = (bf16_t)(v - (float)h);
}
static __device__ __forceinline__ bf16x8 bzero8() {
    bf16x8 v = {(bf16_t)0.f,(bf16_t)0.f,(bf16_t)0.f,(bf16_t)0.f,
                (bf16_t)0.f,(bf16_t)0.f,(bf16_t)0.f,(bf16_t)0.f};
    return v;
}
// async global->LDS, 16B per lane; LDS dest is wave-uniform base + lane*16,
// global source is PER-LANE.
static __device__ __forceinline__ void gload16(const void* g, void* l) {
    __builtin_amdgcn_global_load_lds(
        (const __attribute__((address_space(1))) unsigned int*)g,
        (__attribute__((address_space(3))) unsigned int*)l, 16, 0, 0);
}
// m204 bijective XCD swizzle
static __device__ __forceinline__ int xcd_swz(int nwg) {
    int orig = blockIdx.x;
    int q = nwg >> 3, r = nwg & 7;
    int xcd = orig & 7, within = orig >> 3;
    int base = (xcd < r) ? xcd*(q+1) : r*(q+1) + (xcd - r)*q;
    return base + within;
}
// reconstruct LN terms from 6 partial sums (slots stride NROWS)
static __device__ __forceinline__ void ln_from_partials(const float* ss, const float* ss2,
                                                        int row, float& mu, float& rstd) {
    float s = 0.f, q2 = 0.f;
    #pragma unroll
    for (int k = 0; k < 6; ++k) { s += ss[k*NROWS + row]; q2 += ss2[k*NROWS + row]; }
    mu = s * (1.f/DD);
    float var = q2 * (1.f/DD) - mu*mu;
    rstd = rsqrtf(var + 1e-5f);
}

// ---------------------------------------------------------------- build x (split residual + ln1 stats)
__global__ __launch_bounds__(256) void build_x_kernel(const float* __restrict__ search,
                               const float* __restrict__ target,
                               const float* __restrict__ cls,
                               const float* __restrict__ spos,
                               const float* __restrict__ tpos,
                               bf16_t* __restrict__ xh, bf16_t* __restrict__ xl,
                               float* __restrict__ wss, float* __restrict__ wss2) {
    int wave = threadIdx.x >> 6, lane = threadIdx.x & 63;
    int row = blockIdx.x * 4 + wave;
    if (row >= NROWS) return;
    int b = row / NSEQ, n = row % NSEQ;
    float s = 0.f, q2 = 0.f;
    #pragma unroll
    for (int i = 0; i < 6; ++i) {
        int d = lane + 64*i;
        float val;
        if (n == 0)        val = cls[d];
        else if (n <= 576) val = search[((size_t)b*576 + (n-1))*DD + d] + spos[(size_t)(n-1)*DD + d];
        else               val = target[((size_t)b*144 + (n-577))*DD + d] + tpos[(size_t)(n-577)*DD + d];
        bf16_t h, l;
        split_bf16(val, h, l);
        xh[(size_t)row*DD + d] = h;
        xl[(size_t)row*DD + d] = l;
        s += val; q2 += val*val;
    }
    #pragma unroll
    for (int m = 1; m < 64; m <<= 1) { s += __shfl_xor(s, m); q2 += __shfl_xor(q2, m); }
    if (lane == 0) {
        wss[row] = s; wss2[row] = q2;
        #pragma unroll
        for (int k = 1; k < 6; ++k) { wss[k*NROWS + row] = 0.f; wss2[k*NROWS + row] = 0.f; }
    }
}

// ---------------------------------------------------------------- weight prep
__global__ void transpose_split_kernel(const float* __restrict__ src,
                                       const float* __restrict__ g,
                                       bf16_t* __restrict__ dh,
                                       bf16_t* __restrict__ dl,
                                       int K, int N) {
    int idx = blockIdx.x * blockDim.x + threadIdx.x;
    if (idx >= K*N) return;
    int k = idx / N, n = idx % N;
    float v = src[idx];
    if (g) v *= g[k];
    bf16_t h, l;
    split_bf16(v, h, l);
    dh[(size_t)n*K + k] = h;
    dl[(size_t)n*K + k] = l;
}

// colsums for LN-fold
__global__ void colsum_kernel(const float* __restrict__ W, const float* __restrict__ g,
                              const float* __restrict__ b, const float* __restrict__ bias,
                              float* __restrict__ c1, float* __restrict__ c2,
                              int K, int N, int outStride, int outOff) {
    int l = blockIdx.y;
    int n = blockIdx.x * 256 + threadIdx.x;
    if (n >= N) return;
    const float* Wl = W + (size_t)l*K*N;
    const float* gl = g + (size_t)l*K;
    const float* bl = b + (size_t)l*K;
    float s1 = 0.f, s2 = 0.f;
    for (int k = 0; k < K; ++k) {
        float w = Wl[(size_t)k*N + n];
        s1 = fmaf(gl[k], w, s1);
        s2 = fmaf(bl[k], w, s2);
    }
    c1[(size_t)l*outStride + outOff + n] = s1;
    c2[(size_t)l*outStride + outOff + n] = s2 + bias[(size_t)l*N + n];
}

// ---------------------------------------------------------------- GEMM core
// Serial single-buffer (32KB LDS), 4 blocks/CU (proven best: rounds 8 vs 5/9).
static __device__ __forceinline__ void gemm_core(
        const bf16_t* __restrict__ ah, const bf16_t* __restrict__ al,
        const bf16_t* __restrict__ bh, const bf16_t* __restrict__ bl,
        bf16_t (&ls)[32][64][8],
        int m0, int n0, int K, f32x4 (&acc)[4][4]) {
    int t = threadIdx.x;
    int w = t >> 6, lane = t & 63;
    int c = lane & 15, g = lane >> 4;
    int wr = w >> 1, wc = w & 1;
    const bf16_t* src0 = (w==0) ? ah : (w==1) ? al : (w==2) ? bh : bl;
    int base_rc = (w < 2) ? m0 : n0;
    const bf16_t* srcbase = src0 + (size_t)(base_rc + c)*K + 8*g;

    int ksteps = K >> 5;
    for (int kt = 0; kt < ksteps; ++kt) {
        int k0 = kt << 5;
        __syncthreads();
        #pragma unroll
        for (int i = 0; i < 8; ++i)
            gload16(srcbase + (size_t)(16*i)*K + k0, &ls[w*8 + i][0][0]);
        __syncthreads();
        bf16x8 af_h[4], af_l[4], bf_h[4], bf_l[4];
        #pragma unroll
        for (int i = 0; i < 4; ++i) {
            af_h[i] = *(const bf16x8*)&ls[     4*wr + i][lane][0];
            af_l[i] = *(const bf16x8*)&ls[ 8 + 4*wr + i][lane][0];
            bf_h[i] = *(const bf16x8*)&ls[16 + 4*wc + i][lane][0];
            bf_l[i] = *(const bf16x8*)&ls[24 + 4*wc + i][lane][0];
        }
        #pragma unroll
        for (int i = 0; i < 4; ++i)
            #pragma unroll
            for (int j = 0; j < 4; ++j) {
                acc[i][j] = __builtin_amdgcn_mfma_f32_16x16x32_bf16(af_h[i], bf_h[j], acc[i][j], 0,0,0);
                acc[i][j] = __builtin_amdgcn_mfma_f32_16x16x32_bf16(af_h[i], bf_l[j], acc[i][j], 0,0,0);
                acc[i][j] = __builtin_amdgcn_mfma_f32_16x16x32_bf16(af_l[i], bf_h[j], acc[i][j], 0,0,0);
            }
    }
}

// ---------------------------------------------------------------- fused QKV GEMM (LN-folded)
// Batch-aligned m-tiles (6/batch). ALL outputs coalesced via in-LDS regroup:
//  Q/K: row-major regroup (no transpose), 16B stores.
//  V:   transpose to per-batch [d][VTW], bf16-hi ONLY, pad tokens zeroed
//       (NaN-garbage in pad would poison PV; round-11 lesson).
__global__ __launch_bounds__(256, 4) void gemm_qkv(
        const bf16_t* __restrict__ ah, const bf16_t* __restrict__ al,
        const bf16_t* __restrict__ bh, const bf16_t* __restrict__ bl,
        const float* __restrict__ ss, const float* __restrict__ ss2,
        const float* __restrict__ c1, const float* __restrict__ c2,
        bf16_t* __restrict__ qout, bf16_t* __restrict__ kout,
        bf16_t* __restrict__ vth,
        int nwg) {
    __shared__ __align__(16) bf16_t ls[32][64][8];
    int wgid = xcd_swz(nwg);
    int mt = wgid / 9, n0 = (wgid % 9) * 128;
    int blb = mt / 6;
    int tok_base = (mt % 6) * 128;
    int m0d = blb*NSEQ + tok_base;           // contiguous data rows (tail reads spill, discarded)
    f32x4 zero4 = {0.f,0.f,0.f,0.f};
    f32x4 acc[4][4];
    #pragma unroll
    for (int i = 0; i < 4; ++i)
        #pragma unroll
        for (int j = 0; j < 4; ++j) acc[i][j] = zero4;
    gemm_core(ah, al, bh, bl, ls, m0d, n0, DD, acc);

    int t = threadIdx.x, w = t >> 6, lane = t & 63;
    int c = lane & 15, g = lane >> 4;
    int wr = w >> 1, wc = w & 1;
    // hoisted per-row LN terms (valid tokens only)
    float rmu[16], rrs[16];
    #pragma unroll
    for (int i = 0; i < 4; ++i)
        #pragma unroll
        for (int r = 0; r < 4; ++r) {
            int tok = tok_base + 64*wr + 16*i + 4*g + r;
            float mu = 0.f, rstd = 1.f;
            if (tok < NSEQ) ln_from_partials(ss, ss2, blb*NSEQ + tok, mu, rstd);
            rmu[i*4+r] = mu; rrs[i*4+r] = rstd;
        }
    int seg = n0 / 384;                      // 0=Q 1=K 2=V
    bf16_t* LST = &ls[0][0][0];              // 128x128 bf16 regroup buffer (32KB)
    if (seg < 2) {
        bf16_t* outb = (seg == 0) ? qout : kout;
        int segoff = seg * 384;
        __syncthreads();                     // core done reading ls
        #pragma unroll
        for (int j = 0; j < 4; ++j) {
            int nl = 64*wc + 16*j + c;       // tile-local n 0..127
            float C1 = c1[n0 + nl], C2 = c2[n0 + nl];
            #pragma unroll
            for (int i = 0; i < 4; ++i)
                #pragma unroll
                for (int r = 0; r < 4; ++r) {
                    int rl = 64*wr + 16*i + 4*g + r;   // tile-local row 0..127
                    float val = rrs[i*4+r]*(acc[i][j][r] - rmu[i*4+r]*C1) + C2;
                    LST[rl*128 + (nl ^ ((rl & 15) << 3))] = (bf16_t)val;
                }
        }
        __syncthreads();
        #pragma unroll
        for (int p = 0; p < 8; ++p) {
            int chunk = t + 256*p;
            int rl = chunk >> 4;
            int nl0 = (chunk & 15) * 8;
            int tok = tok_base + rl;
            if (tok >= NSEQ) continue;
            uint4 v = *(const uint4*)&LST[rl*128 + (nl0 ^ ((rl & 15) << 3))];
            *(uint4*)(outb + (size_t)(blb*NSEQ + tok)*DD + (n0 - segoff) + nl0) = v;
        }
    } else {
        int vbase = n0 - 768;                // 0 / 128 / 256
        __syncthreads();                     // core done reading ls
        #pragma unroll
        for (int j = 0; j < 4; ++j) {
            int d = 64*wc + 16*j + c;
            float C1 = c1[n0 + d], C2 = c2[n0 + d];
            #pragma unroll
            for (int i = 0; i < 4; ++i)
                #pragma unroll
                for (int r = 0; r < 4; ++r) {
                    int tokl = 64*wr + 16*i + 4*g + r;   // local 0..127
                    float val = rrs[i*4+r]*(acc[i][j][r] - rmu[i*4+r]*C1) + C2;
                    if (tok_base + tokl >= NSEQ) val = 0.f;   // kill NaN garbage in pad
                    LST[d*128 + (tokl ^ ((d & 15) << 3))] = (bf16_t)val;
                }
        }
        __syncthreads();
        #pragma unroll
        for (int p = 0; p < 8; ++p) {
            int chunk = t + 256*p;
            int d = chunk >> 4;
            int tok0 = (chunk & 15) * 8;
            int tg = tok_base + tok0;
            if (tg + 8 > VTW) continue;      // don't spill into next d-row
            uint4 v = *(const uint4*)&LST[d*128 + (tok0 ^ ((d & 15) << 3))];
            *(uint4*)(vth + ((size_t)(blb*DD + vbase + d))*VTW + tg) = v;
        }
    }
}

// ---------------------------------------------------------------- MLP GEMMs
// EPI 2 (LN-folded): gelu -> hi/lo [M][768] scalar stores
// EPI 3: bias + res -> split residual out + ln2-stat partials
template<int EPI, int NT>
__global__ __launch_bounds__(256, 4) void gemm_mfma(
        const bf16_t* __restrict__ ah, const bf16_t* __restrict__ al,
        const bf16_t* __restrict__ bh, const bf16_t* __restrict__ bl,
        const float* __restrict__ ss, const float* __restrict__ ss2,
        const float* __restrict__ c1, const float* __restrict__ c2,
        const float* __restrict__ bias,
        const bf16_t* __restrict__ resh, const bf16_t* __restrict__ resl,
        bf16_t* __restrict__ o1, bf16_t* __restrict__ o2,
        float* __restrict__ wss, float* __restrict__ wss2,
        int M, int N, int K, int nwg) {
    __shared__ __align__(16) bf16_t ls[32][64][8];
    int wgid = xcd_swz(nwg);
    int m0 = (wgid / NT) * 128, n0 = (wgid % NT) * 128;
    f32x4 zero4 = {0.f,0.f,0.f,0.f};
    f32x4 acc[4][4];
    #pragma unroll
    for (int i = 0; i < 4; ++i)
        #pragma unroll
        for (int j = 0; j < 4; ++j) acc[i][j] = zero4;
    gemm_core(ah, al, bh, bl, ls, m0, n0, K, acc);

    int t = threadIdx.x, w = t >> 6, lane = t & 63;
    int c = lane & 15, g = lane >> 4;
    int wr = w >> 1, wc = w & 1;

    if (EPI == 2) {
        float rmu[16], rrs[16];
        #pragma unroll
        for (int i = 0; i < 4; ++i)
            #pragma unroll
            for (int r = 0; r < 4; ++r) {
                int row = m0 + 64*wr + 16*i + 4*g + r;
                float mu = 0.f, rstd = 1.f;
                if (row < M) ln_from_partials(ss, ss2, row, mu, rstd);
                rmu[i*4+r] = mu; rrs[i*4+r] = rstd;
            }
        #pragma unroll
        for (int j = 0; j < 4; ++j) {
            int n = n0 + 64*wc + 16*j + c;
            float C1 = c1[n], C2 = c2[n];
            #pragma unroll
            for (int i = 0; i < 4; ++i) {
                int rbase = m0 + 64*wr + 16*i + 4*g;
                #pragma unroll
                for (int r = 0; r < 4; ++r) {
                    int row = rbase + r;
                    if (row >= M) continue;
                    float val = rrs[i*4+r]*(acc[i][j][r] - rmu[i*4+r]*C1) + C2;
                    val = 0.5f*val*(1.0f + erff(val*0.70710678118654752f));
                    bf16_t h, l;
                    split_bf16(val, h, l);
                    size_t o = (size_t)row*N + n;
                    o1[o] = h;
                    o2[o] = l;
                }
            }
        }
    } else {
        int slot = (wgid % NT) + 3*wc;       // NT==3: slots 0..5
        #pragma unroll
        for (int i = 0; i < 4; ++i)
            #pragma unroll
            for (int r = 0; r < 4; ++r) {
                int row = m0 + 64*wr + 16*i + 4*g + r;
                if (row >= M) continue;
                float s = 0.f, q2 = 0.f;
                #pragma unroll
                for (int j = 0; j < 4; ++j) {
                    int n = n0 + 64*wc + 16*j + c;
                    size_t o = (size_t)row*N + n;
                    float val = acc[i][j][r] + bias[n] + (float)resh[o] + (float)resl[o];
                    bf16_t h, l;
                    split_bf16(val, h, l);
                    o1[o] = h;
                    o2[o] = l;
                    s += val; q2 += val*val;
                }
                #pragma unroll
                for (int m = 1; m < 16; m <<= 1) { s += __shfl_xor(s, m); q2 += __shfl_xor(q2, m); }
                if (c == 0) {
                    wss[slot*NROWS + row] = s;
                    wss2[slot*NROWS + row] = q2;
                }
            }
    }
}

// ---------------------------------------------------------------- MFMA attention
// 4 waves / 64 q-rows; K + V-hi DMA-staged (48KB LDS). __launch_bounds__(256,2)
// pins 2 blk/CU (proven L2-friendly residency; rounds 12-15 A/B).
// PV 2-pass Vh*(Ph+Pl); defer-max (T13).
__global__ __launch_bounds__(256, 2) void attn_mfma(
        const bf16_t* __restrict__ qh, const bf16_t* __restrict__ kh,
        const bf16_t* __restrict__ vth,
        bf16_t* __restrict__ xh, bf16_t* __restrict__ xl,
        float* __restrict__ wss, float* __restrict__ wss2, int nwg) {
    __shared__ __align__(16) char smem[49152];
    bf16_t* kf = (bf16_t*)smem;              // 24 slots x 1KB  (K tile)
    char* vhp = smem + 24576;                // 24KB V-hi

    int t = threadIdx.x, w = t >> 6, lane = t & 63;
    int c = lane & 15, g = lane >> 4;
    int wgid = xcd_swz(nwg);
    int bl_ = wgid / 12;
    int q0 = (wgid % 12) * 64;
    size_t bb = (size_t)bl_ * NSEQ;
    int qrow = q0 + 16*w + c;
    bool qok = (qrow < NSEQ);
    const float scale = 0.05103103630798287f;   // 384^-0.5
    int vswz = (c ^ (c >> 2)) & 3;              // PV read slot swizzle
    int dma_dd  = lane >> 2;                    // V DMA lane mapping
    int dma_kv8 = (lane & 3) ^ ((dma_dd ^ (dma_dd >> 2)) & 3);

    bf16x8 qf[12];
    #pragma unroll
    for (int ks = 0; ks < 12; ++ks) {
        if (qok) qf[ks] = *(const bf16x8*)(qh + (bb + qrow)*DD + 32*ks + 8*g);
        else     qf[ks] = bzero8();
    }

    f32x4 zero4 = {0.f,0.f,0.f,0.f};
    f32x4 oacc[24];
    #pragma unroll
    for (int i = 0; i < 24; ++i) oacc[i] = zero4;
    float m_run = -1e30f, l_run = 0.f;

    // prologue: issue K(0)
    #pragma unroll
    for (int i = 0; i < 6; ++i) {
        int s = i*4 + w;
        int ks = s >> 1, mf = s & 1;
        gload16(kh + (bb + (size_t)(16*mf + c))*DD + 32*ks + 8*g, kf + s*512);
    }

    for (int kt = 0; kt < 23; ++kt) {
        int kv0 = kt * 32;
        asm volatile("s_waitcnt vmcnt(0)" ::: "memory");   // K(kt) landed
        __builtin_amdgcn_s_barrier();
        // issue V(kt): flight hides under QK+softmax
        #pragma unroll
        for (int i = 0; i < 6; ++i) {
            int s = i*4 + w;
            size_t gro = ((size_t)(bl_*DD + 16*s + dma_dd))*VTW + kv0 + 8*dma_kv8;
            gload16(vth + gro, (bf16_t*)vhp + s*512);
        }
        // ---- QK: S^T = K * Q^T
        f32x4 sacc[2];
        sacc[0] = zero4; sacc[1] = zero4;
        #pragma unroll
        for (int ks = 0; ks < 12; ++ks) {
            bf16x8 a0 = *(const bf16x8*)(kf + ((size_t)(2*ks+0)*64 + lane)*8);
            bf16x8 a1 = *(const bf16x8*)(kf + ((size_t)(2*ks+1)*64 + lane)*8);
            sacc[0] = __builtin_amdgcn_mfma_f32_16x16x32_bf16(a0, qf[ks], sacc[0], 0,0,0);
            sacc[1] = __builtin_amdgcn_mfma_f32_16x16x32_bf16(a1, qf[ks], sacc[1], 0,0,0);
        }
        // ---- online softmax with defer-max
        float p[2][4];
        float mx = -1e30f;
        #pragma unroll
        for (int mf = 0; mf < 2; ++mf)
            #pragma unroll
            for (int r = 0; r < 4; ++r) {
                float sv = sacc[mf][r] * scale;
                int kv = kv0 + 16*mf + 4*g + r;
                if (kv >= NSEQ) sv = -1e30f;
                p[mf][r] = sv;
                mx = fmaxf(mx, sv);
            }
        mx = fmaxf(mx, __shfl_xor(mx, 16));
        mx = fmaxf(mx, __shfl_xor(mx, 32));
        bool skip = __all(mx <= m_run + 8.f);   // P bounded by e^8: safe in f32
        float m_new = skip ? m_run : fmaxf(m_run, mx);
        float psum = 0.f;
        #pragma unroll
        for (int mf = 0; mf < 2; ++mf)
            #pragma unroll
            for (int r = 0; r < 4; ++r) {
                float pv = __expf(p[mf][r] - m_new);
                p[mf][r] = pv;
                psum += pv;
            }
        psum += __shfl_xor(psum, 16);
        psum += __shfl_xor(psum, 32);
        if (!skip) {
            float corr = __expf(m_run - m_new);
            l_run = l_run * corr + psum;
            #pragma unroll
            for (int i = 0; i < 24; ++i) oacc[i] *= corr;
            m_run = m_new;
        } else {
            l_run += psum;
        }
        bf16x8 ph, pl;
        #pragma unroll
        for (int mf = 0; mf < 2; ++mf)
            #pragma unroll
            for (int r = 0; r < 4; ++r) {
                bf16_t hh, ll;
                split_bf16(p[mf][r], hh, ll);
                ph[mf*4 + r] = hh;
                pl[mf*4 + r] = ll;
            }
        asm volatile("s_waitcnt vmcnt(0)" ::: "memory");   // V(kt) landed
        __builtin_amdgcn_s_barrier();
        // issue K(kt+1): flight hides under PV
        if (kt + 1 < 23) {
            int kv0n = kv0 + 32;
            #pragma unroll
            for (int i = 0; i < 6; ++i) {
                int s = i*4 + w;
                int ks = s >> 1, mf = s & 1;
                gload16(kh + (bb + (size_t)(kv0n + 16*mf + c))*DD + 32*ks + 8*g, kf + s*512);
            }
        }
        // ---- PV: O^T += Vh^T * (Ph + Pl)  (2-pass)
        #pragma unroll
        for (int mf = 0; mf < 24; ++mf) {
            int dr = 16*mf + c;
            const char* vb = vhp + dr*64;
            int o0 = ((((g>>1)     ^ vswz) << 4) | (8*(g&1)));
            int o1 = (((2 + (g>>1)) ^ vswz) << 4) | (8*(g&1));
            union { uint2 u[2]; bf16x8 v; } va;
            va.u[0] = *(const uint2*)(vb + o0);
            va.u[1] = *(const uint2*)(vb + o1);
            oacc[mf] = __builtin_amdgcn_mfma_f32_16x16x32_bf16(va.v, ph, oacc[mf], 0,0,0);
            oacc[mf] = __builtin_amdgcn_mfma_f32_16x16x32_bf16(va.v, pl, oacc[mf], 0,0,0);
        }
    }
    float inv = 1.f / l_run;
    float s = 0.f, q2 = 0.f;
    if (qok) {
        bf16_t* xhr = xh + (bb + qrow)*DD;
        bf16_t* xlr = xl + (bb + qrow)*DD;
        #pragma unroll
        for (int mf = 0; mf < 24; ++mf)
            #pragma unroll
            for (int r = 0; r < 4; ++r) {
                int d = 16*mf + 4*g + r;
                float xv = (float)xhr[d] + (float)xlr[d] + oacc[mf][r]*inv;
                bf16_t h, l;
                split_bf16(xv, h, l);
                xhr[d] = h;
                xlr[d] = l;
                s += xv; q2 += xv*xv;
            }
    }
    s += __shfl_xor(s, 16);  q2 += __shfl_xor(q2, 16);
    s += __shfl_xor(s, 32);  q2 += __shfl_xor(q2, 32);
    if (qok && g == 0) {
        int rowL = bl_*NSEQ + qrow;
        wss[rowL] = s; wss2[rowL] = q2;
        #pragma unroll
        for (int k = 1; k < 6; ++k) { wss[k*NROWS + rowL] = 0.f; wss2[k*NROWS + rowL] = 0.f; }
    }
}

// ---------------------------------------------------------------- head (f32)
__global__ __launch_bounds__(384) void head_kernel(const bf16_t* __restrict__ xh,
    const bf16_t* __restrict__ xl,
    const float* __restrict__ g, const float* __restrict__ bb,
    const float* __restrict__ Wl1, const float* __restrict__ bl1,
    const float* __restrict__ Wl2, const float* __restrict__ bl2,
    float* __restrict__ outp) {
    __shared__ float yv[384];
    __shared__ float r1[6], r2[6], r3[6];
    int b = blockIdx.x, t = threadIdx.x;
    size_t o = (size_t)b*NSEQ*DD + t;
    float v = (float)xh[o] + (float)xl[o];
    float s = v;
    #pragma unroll
    for (int m = 1; m < 64; m <<= 1) s += __shfl_xor(s, m);
    if ((t & 63) == 0) r1[t>>6] = s;
    __syncthreads();
    float mu = (r1[0]+r1[1]+r1[2]+r1[3]+r1[4]+r1[5]) * (1.f/384.f);
    float dd = v - mu;
    float sq = dd*dd;
    #pragma unroll
    for (int m = 1; m < 64; m <<= 1) sq += __shfl_xor(sq, m);
    if ((t & 63) == 0) r2[t>>6] = sq;
    __syncthreads();
    float var = (r2[0]+r2[1]+r2[2]+r2[3]+r2[4]+r2[5]) * (1.f/384.f);
    float rstd = rsqrtf(var + 1e-5f);
    yv[t] = dd*rstd*g[t] + bb[t];
    __syncthreads();
    float acc = bl1[t];
    for (int d2 = 0; d2 < 384; d2++) acc = fmaf(yv[d2], Wl1[d2*384 + t], acc);
    acc = fmaxf(acc, 0.f);
    float oo = acc * Wl2[t];
    #pragma unroll
    for (int m = 1; m < 64; m <<= 1) oo += __shfl_xor(oo, m);
    if ((t & 63) == 0) r3[t>>6] = oo;
    __syncthreads();
    if (t == 0) outp[b] = r3[0]+r3[1]+r3[2]+r3[3]+r3[4]+r3[5] + bl2[0];
}

// ---------------------------------------------------------------- launch
extern "C" void kernel_launch(void* const* d_in, const int* in_sizes, int n_in,
                              void* d_out, int out_size, void* d_ws, size_t ws_size,
                              hipStream_t stream) {
    const float* search = (const float*)d_in[0];
    const float* target = (const float*)d_in[1];
    const float* cls    = (const float*)d_in[2];
    const float* spos   = (const float*)d_in[3];
    const float* tpos   = (const float*)d_in[4];
    const float* ln1_g  = (const float*)d_in[5];
    const float* ln1_b  = (const float*)d_in[6];
    const float* Wq     = (const float*)d_in[7];
    const float* bq     = (const float*)d_in[8];
    const float* Wk     = (const float*)d_in[9];
    const float* bk     = (const float*)d_in[10];
    const float* Wv     = (const float*)d_in[11];
    const float* bv     = (const float*)d_in[12];
    const float* ln2_g  = (const float*)d_in[13];
    const float* ln2_b  = (const float*)d_in[14];
    const float* W1     = (const float*)d_in[15];
    const float* b1     = (const float*)d_in[16];
    const float* W2     = (const float*)d_in[17];
    const float* b2     = (const float*)d_in[18];
    const float* lnf_g  = (const float*)d_in[19];
    const float* lnf_b  = (const float*)d_in[20];
    const float* Wl1    = (const float*)d_in[21];
    const float* bl1    = (const float*)d_in[22];
    const float* Wl2    = (const float*)d_in[23];
    const float* bl2    = (const float*)d_in[24];

    size_t off = 0;
    char* base = (char*)d_ws;
    auto alloc = [&](size_t bytes) -> void* {
        void* p = base + off;
        off += (bytes + 255) & ~(size_t)255;
        return p;
    };

    bf16_t* xh = (bf16_t*)alloc((size_t)NROWS * DD * 2);
    bf16_t* xl = (bf16_t*)alloc((size_t)NROWS * DD * 2);
    float* ssum  = (float*)alloc((size_t)6*NROWS*4);
    float* ssum2 = (float*)alloc((size_t)6*NROWS*4);

    const int SQKV = 1152*DD;
    const int SM = DD*768;
    bf16_t* wqkvh = (bf16_t*)alloc((size_t)4*SQKV*2);
    bf16_t* wqkvl = (bf16_t*)alloc((size_t)4*SQKV*2);
    bf16_t* w1h = (bf16_t*)alloc((size_t)4*SM*2);
    bf16_t* w1l = (bf16_t*)alloc((size_t)4*SM*2);
    bf16_t* w2h = (bf16_t*)alloc((size_t)4*SM*2);
    bf16_t* w2l = (bf16_t*)alloc((size_t)4*SM*2);
    float* cqkv1 = (float*)alloc((size_t)4*1152*4);
    float* cqkv2 = (float*)alloc((size_t)4*1152*4);
    float* cm11  = (float*)alloc((size_t)4*768*4);
    float* cm12  = (float*)alloc((size_t)4*768*4);

    // union workspace: {q,k,vt-hi} aliases {midh,midl}; mid dominates.
    const size_t qB  = (size_t)NSEQ*DD*2;     // 553,728
    const size_t mB  = (size_t)NSEQ*768*2;    // 1,107,456
    const size_t perB = 2*mB;                 // >= 2*qB + vB
    size_t avail = (ws_size > off + 262144) ? (ws_size - off - 262144) : 0;
    int G = (int)(avail / perB);
    if (G > NBATCH) G = NBATCH;
    if (G < 1) G = 1;

    char* U = (char*)alloc(perB * G);
    bf16_t* qhB  = (bf16_t*)U;
    bf16_t* khB  = (bf16_t*)(U + qB*G);
    bf16_t* vth  = (bf16_t*)(U + 2*qB*G);
    bf16_t* midh = (bf16_t*)U;
    bf16_t* midl = (bf16_t*)(U + mB*G);

    build_x_kernel<<<(NROWS+3)/4, 256, 0, stream>>>(search, target, cls, spos, tpos,
                                                    xh, xl, ssum, ssum2);

    const int SQ = DD*DD;
    for (int l = 0; l < NLAYER; ++l) {
        bf16_t* dsth = wqkvh + (size_t)l*SQKV;
        bf16_t* dstl = wqkvl + (size_t)l*SQKV;
        transpose_split_kernel<<<(SQ+255)/256, 256, 0, stream>>>(Wq + (size_t)l*SQ, ln1_g + l*DD, dsth,          dstl,          DD, DD);
        transpose_split_kernel<<<(SQ+255)/256, 256, 0, stream>>>(Wk + (size_t)l*SQ, ln1_g + l*DD, dsth + 384*DD, dstl + 384*DD, DD, DD);
        transpose_split_kernel<<<(SQ+255)/256, 256, 0, stream>>>(Wv + (size_t)l*SQ, ln1_g + l*DD, dsth + 768*DD, dstl + 768*DD, DD, DD);
        transpose_split_kernel<<<(SM+255)/256, 256, 0, stream>>>(W1 + (size_t)l*SM, ln2_g + l*DD, w1h + (size_t)l*SM, w1l + (size_t)l*SM, DD, 768);
        transpose_split_kernel<<<(SM+255)/256, 256, 0, stream>>>(W2 + (size_t)l*SM, nullptr,      w2h + (size_t)l*SM, w2l + (size_t)l*SM, 768, DD);
    }
    colsum_kernel<<<dim3(2, NLAYER), 256, 0, stream>>>(Wq, ln1_g, ln1_b, bq, cqkv1, cqkv2, DD, DD, 1152, 0);
    colsum_kernel<<<dim3(2, NLAYER), 256, 0, stream>>>(Wk, ln1_g, ln1_b, bk, cqkv1, cqkv2, DD, DD, 1152, 384);
    colsum_kernel<<<dim3(2, NLAYER), 256, 0, stream>>>(Wv, ln1_g, ln1_b, bv, cqkv1, cqkv2, DD, DD, 1152, 768);
    colsum_kernel<<<dim3(3, NLAYER), 256, 0, stream>>>(W1, ln2_g, ln2_b, b1, cm11, cm12, DD, 768, 768, 0);

    for (int l = 0; l < NLAYER; ++l) {
        for (int b0 = 0; b0 < NBATCH; b0 += G) {
            int cb = (NBATCH - b0 < G) ? (NBATCH - b0) : G;
            int Mc = cb * NSEQ;
            bf16_t* xch = xh + (size_t)b0 * NSEQ * DD;
            bf16_t* xcl = xl + (size_t)b0 * NSEQ * DD;
            float* ssc  = ssum  + (size_t)b0 * NSEQ;
            float* ssc2 = ssum2 + (size_t)b0 * NSEQ;
            int mtiles = (Mc + 127)/128;
            int nwgQKV = 9*6*cb, nwgM1 = 6*mtiles, nwgM2 = 3*mtiles, nwgA = 12*cb;

            gemm_qkv<<<nwgQKV, 256, 0, stream>>>(xch, xcl,
                    wqkvh + (size_t)l*SQKV, wqkvl + (size_t)l*SQKV,
                    ssc, ssc2, cqkv1 + l*1152, cqkv2 + l*1152,
                    qhB, khB, vth, nwgQKV);
            attn_mfma<<<nwgA, 256, 0, stream>>>(qhB, khB, vth, xch, xcl,
                    ssc, ssc2, nwgA);
            gemm_mfma<2,6><<<nwgM1, 256, 0, stream>>>(xch, xcl,
                    w1h + (size_t)l*SM, w1l + (size_t)l*SM,
                    ssc, ssc2, cm11 + l*768, cm12 + l*768, nullptr,
                    nullptr, nullptr, midh, midl, nullptr, nullptr, Mc, 768, DD, nwgM1);
            gemm_mfma<3,3><<<nwgM2, 256, 0, stream>>>(midh, midl,
                    w2h + (size_t)l*SM, w2l + (size_t)l*SM,
                    nullptr, nullptr, nullptr, nullptr, b2 + l*DD,
                    xch, xcl, xch, xcl, ssc, ssc2, Mc, DD, 768, nwgM2);
        }
    }
    head_kernel<<<NBATCH, 384, 0, stream>>>(xh, xl, lnf_g, lnf_b, Wl1, bl1, Wl2, bl2, (float*)d_out);
}